// Round 7
// baseline (1902.129 us; speedup 1.0000x reference)
//
#include <hip/hip_runtime.h>
#include <hip/hip_bf16.h>

#define Bn  128
#define Ln  256
#define En  300
#define Hn  128
#define Cn  4
#define Dn  256     // 2H
#define G3n 384     // 3H
#define BLn (Bn * Ln)   // 32768

typedef __hip_bfloat16 bf16;
typedef short s16x8 __attribute__((ext_vector_type(8)));
typedef float f32x4 __attribute__((ext_vector_type(4)));

__device__ __forceinline__ float ldf(const float* p) { return *p; }
__device__ __forceinline__ float ldf(const bf16* p)  { return __bfloat162float(*p); }
__device__ __forceinline__ void stf(float* p, float v) { *p = v; }
__device__ __forceinline__ void stf(bf16* p, float v)  { *p = __float2bfloat16(v); }

__device__ __forceinline__ ushort f2bf(float f) {
    bf16 h = __float2bfloat16(f);
    return *reinterpret_cast<ushort*>(&h);
}

// ---------------------------------------------------------------------------
// MFMA bf16 GEMM: C[M,N] = A[M,K] * W^T + bias   (W is (N,K) row-major)
//   GATHER: A row m = A[gidx[m]*K ..]    SM==1: store C[(m>>8),n,(m&255)]
// 128x128 tile, 4 waves (2x2 of 64x64), BK=32, LDS rows padded to 40 bf16.
// ---------------------------------------------------------------------------
template<class OT, bool GATHER, int SM>
__global__ __launch_bounds__(256)
void gemm_mfma(const float* __restrict__ A, const float* __restrict__ W,
               const float* __restrict__ bias, OT* __restrict__ Cout,
               const int* __restrict__ gidx, int M, int N, int K)
{
    __shared__ ushort Asm[128 * 40];
    __shared__ ushort Bsm[128 * 40];
    const int bm = blockIdx.y * 128, bn = blockIdx.x * 128;
    const int tid = threadIdx.x;
    const int lane = tid & 63, w = tid >> 6, wr = w >> 1, wc = w & 1;

    const float* arow[4];
    const float* brow[4];
#pragma unroll
    for (int u = 0; u < 4; ++u) {
        const int idx = tid + u * 256;
        const int m = idx >> 3;
        arow[u] = A + (size_t)(GATHER ? gidx[bm + m] : (bm + m)) * K;
        brow[u] = W + (size_t)(bn + m) * K;
    }

    f32x4 acc[4][4] = {};
    const int nkt = (K + 31) >> 5;
    for (int kt = 0; kt < nkt; ++kt) {
        const int k0 = kt << 5;
#pragma unroll
        for (int u = 0; u < 4; ++u) {
            const int idx = tid + u * 256;
            const int m = idx >> 3, kq = idx & 7;
            const int kb = k0 + kq * 4;
            float4 v, q;
            if (kb + 4 <= K) {
                v = *(const float4*)(arow[u] + kb);
                q = *(const float4*)(brow[u] + kb);
            } else {
                v.x = kb + 0 < K ? arow[u][kb + 0] : 0.f;
                v.y = kb + 1 < K ? arow[u][kb + 1] : 0.f;
                v.z = kb + 2 < K ? arow[u][kb + 2] : 0.f;
                v.w = kb + 3 < K ? arow[u][kb + 3] : 0.f;
                q.x = kb + 0 < K ? brow[u][kb + 0] : 0.f;
                q.y = kb + 1 < K ? brow[u][kb + 1] : 0.f;
                q.z = kb + 2 < K ? brow[u][kb + 2] : 0.f;
                q.w = kb + 3 < K ? brow[u][kb + 3] : 0.f;
            }
            *(ushort4*)&Asm[m * 40 + kq * 4] =
                make_ushort4(f2bf(v.x), f2bf(v.y), f2bf(v.z), f2bf(v.w));
            *(ushort4*)&Bsm[m * 40 + kq * 4] =
                make_ushort4(f2bf(q.x), f2bf(q.y), f2bf(q.z), f2bf(q.w));
        }
        __syncthreads();
        s16x8 af[4], bfr[4];
#pragma unroll
        for (int t = 0; t < 4; ++t) {
            af[t]  = *(const s16x8*)&Asm[(wr * 64 + t * 16 + (lane & 15)) * 40 + (lane >> 4) * 8];
            bfr[t] = *(const s16x8*)&Bsm[(wc * 64 + t * 16 + (lane & 15)) * 40 + (lane >> 4) * 8];
        }
#pragma unroll
        for (int mf = 0; mf < 4; ++mf)
#pragma unroll
            for (int nf = 0; nf < 4; ++nf)
                acc[mf][nf] = __builtin_amdgcn_mfma_f32_16x16x32_bf16(
                    af[mf], bfr[nf], acc[mf][nf], 0, 0, 0);
        __syncthreads();
    }

#pragma unroll
    for (int mf = 0; mf < 4; ++mf)
#pragma unroll
        for (int nf = 0; nf < 4; ++nf) {
            const int col = bn + wc * 64 + nf * 16 + (lane & 15);
            const float bv_ = bias ? bias[col] : 0.f;
#pragma unroll
            for (int i = 0; i < 4; ++i) {
                const int row = bm + wr * 64 + mf * 16 + (lane >> 4) * 4 + i;
                const float v = acc[mf][nf][i] + bv_;
                if (SM == 1)
                    stf(&Cout[((size_t)(row >> 8) * N + col) * 256 + (row & 255)], v);
                else
                    stf(&Cout[(size_t)row * N + col], v);
            }
        }
}

// ---------------------------------------------------------------------------
// GRU scan v4: MFMA-batched. Block = (16 batches, dir), 512 thr / 8 waves.
// Per step: G[16x384] = H[16x128] @ W_hh^T via mfma_16x16x32_bf16; each wave
// owns 3 n-tiles (48 gates) as 12 one-time B-frags in VGPRs (MFMA operands
// cannot be demoted; pointers deliberately NOT __restrict__ so the compiler
// may not re-materialize the weight loads past the in-loop global stores --
// round-5/6 post-mortems: scalar versions kept re-streaming weights from
// L2/scratch at ~340us). H state fp32 in LDS (no error accumulation); gates
// via padded G_lds; gx loads issued pre-MFMA to hide HBM latency.
// ---------------------------------------------------------------------------
__global__ __launch_bounds__(512, 2)
void gru_scan_mfma(const bf16* gx, const float* w_hh,
                   const float* b_hh, float* out)
{
    const int bg = blockIdx.x, dir = blockIdx.y;
    const int tid = threadIdx.x, lane = tid & 63, w = tid >> 6;
    const int ncol = lane & 15, kgrp = lane >> 4;
    __shared__ float h_lds[16][132];     // +4 pad: 2-way max on A-frag reads
    __shared__ float G_lds[16][388];     // +4 pad: conflict-free G writes

    // one-time: B-frags = W_hh^T, 3 n-tiles x 4 k-tiles per wave
    s16x8 bfrag[3][4];
#pragma unroll
    for (int ntl = 0; ntl < 3; ++ntl) {
        const int ng = (w * 3 + ntl) * 16 + ncol;              // gate row 0..383
        const float* wr = w_hh + ((size_t)dir * G3n + ng) * Hn + kgrp * 8;
#pragma unroll
        for (int kt = 0; kt < 4; ++kt) {
            const float4 v0 = *(const float4*)(wr + kt * 32);
            const float4 v1 = *(const float4*)(wr + kt * 32 + 4);
            s16x8 f;
            f[0] = (short)f2bf(v0.x); f[1] = (short)f2bf(v0.y);
            f[2] = (short)f2bf(v0.z); f[3] = (short)f2bf(v0.w);
            f[4] = (short)f2bf(v1.x); f[5] = (short)f2bf(v1.y);
            f[6] = (short)f2bf(v1.z); f[7] = (short)f2bf(v1.w);
            bfrag[ntl][kt] = f;
        }
    }

    const int j  = tid & 127;            // gate column owned in gate phase
    const int m0 = tid >> 7;             // batch base (m = m0 + 4p)
    const float bhr = b_hh[dir * G3n + j];
    const float bhz = b_hh[dir * G3n + 128 + j];
    const float bhn = b_hh[dir * G3n + 256 + j];

    for (int i = tid; i < 16 * 132; i += 512) ((float*)h_lds)[i] = 0.f;
    __syncthreads();

    for (int s = 0; s < Ln; ++s) {
        const int t = dir ? (Ln - 1 - s) : s;

        // issue gx loads early; consumed after the barrier (latency hidden)
        float gr[4], gz[4], gn_[4];
#pragma unroll
        for (int p = 0; p < 4; ++p) {
            const size_t go = (((size_t)(bg * 16 + m0 + p * 4) * Ln + t) * 768)
                              + (size_t)dir * G3n + j;
            gr[p]  = ldf(&gx[go]);
            gz[p]  = ldf(&gx[go + 128]);
            gn_[p] = ldf(&gx[go + 256]);
        }

        // A-frags (H -> bf16 on the fly) + 12 MFMA
        f32x4 acc0 = {}, acc1 = {}, acc2 = {};
#pragma unroll
        for (int kt = 0; kt < 4; ++kt) {
            const float* hp = &h_lds[ncol][kt * 32 + kgrp * 8];
            const float4 h0 = *(const float4*)hp;
            const float4 h1 = *(const float4*)(hp + 4);
            s16x8 a;
            a[0] = (short)f2bf(h0.x); a[1] = (short)f2bf(h0.y);
            a[2] = (short)f2bf(h0.z); a[3] = (short)f2bf(h0.w);
            a[4] = (short)f2bf(h1.x); a[5] = (short)f2bf(h1.y);
            a[6] = (short)f2bf(h1.z); a[7] = (short)f2bf(h1.w);
            acc0 = __builtin_amdgcn_mfma_f32_16x16x32_bf16(a, bfrag[0][kt], acc0, 0, 0, 0);
            acc1 = __builtin_amdgcn_mfma_f32_16x16x32_bf16(a, bfrag[1][kt], acc1, 0, 0, 0);
            acc2 = __builtin_amdgcn_mfma_f32_16x16x32_bf16(a, bfrag[2][kt], acc2, 0, 0, 0);
        }
        // D mapping: row(m) = kgrp*4+i, col(n) = ncol  [verified by gemm_mfma]
#pragma unroll
        for (int i = 0; i < 4; ++i) {
            G_lds[kgrp * 4 + i][(w * 3 + 0) * 16 + ncol] = acc0[i];
            G_lds[kgrp * 4 + i][(w * 3 + 1) * 16 + ncol] = acc1[i];
            G_lds[kgrp * 4 + i][(w * 3 + 2) * 16 + ncol] = acc2[i];
        }
        __syncthreads();

        // gate nonlinearity + state update: thread owns (m0+4p, j)
#pragma unroll
        for (int p = 0; p < 4; ++p) {
            const int m = m0 + p * 4;
            const float rr = 1.f / (1.f + expf(-(gr[p] + G_lds[m][j] + bhr)));
            const float zz = 1.f / (1.f + expf(-(gz[p] + G_lds[m][128 + j] + bhz)));
            const float nn = tanhf(gn_[p] + rr * (G_lds[m][256 + j] + bhn));
            const float hold = h_lds[m][j];
            const float hnew = (1.f - zz) * nn + zz * hold;
            h_lds[m][j] = hnew;
            out[(((size_t)(bg * 16 + m) * Ln + t) * Dn) + dir * Hn + j] = hnew;
        }
        __syncthreads();
    }
}

// ---------------------------------------------------------------------------
// attn score, MFMA: s[b,i] = sum_j tanh( x_b[i,:]·mat_b[j,:] + att_b[c] )
// ---------------------------------------------------------------------------
__global__ __launch_bounds__(256)
void attn_score_mfma(const float* __restrict__ x, const float* __restrict__ matc,
                     const float* __restrict__ attb, int c, float* __restrict__ sout)
{
    const int it = blockIdx.x, b = blockIdx.y;
    const float* A  = x    + ((size_t)b * 256 + it * 128) * 256;
    const float* Bm = matc + (size_t)b * 65536;
    __shared__ ushort Xs[128 * 40];
    __shared__ ushort Ms[128 * 40];
    const int tid = threadIdx.x, lane = tid & 63, w = tid >> 6;
    const float bc = attb[c];
    float psum[2][4] = {};

    for (int jt = 0; jt < 2; ++jt) {
        f32x4 acc[2][8] = {};
        for (int kt = 0; kt < 8; ++kt) {
            const int k0 = kt << 5;
#pragma unroll
            for (int u = 0; u < 4; ++u) {
                const int idx = tid + u * 256;
                const int m = idx >> 3, kq = idx & 7;
                const float4 v = *(const float4*)(A + (size_t)m * 256 + k0 + kq * 4);
                const float4 q = *(const float4*)(Bm + (size_t)(jt * 128 + m) * 256 + k0 + kq * 4);
                *(ushort4*)&Xs[m * 40 + kq * 4] =
                    make_ushort4(f2bf(v.x), f2bf(v.y), f2bf(v.z), f2bf(v.w));
                *(ushort4*)&Ms[m * 40 + kq * 4] =
                    make_ushort4(f2bf(q.x), f2bf(q.y), f2bf(q.z), f2bf(q.w));
            }
            __syncthreads();
            s16x8 af[2], bfr[8];
#pragma unroll
            for (int t = 0; t < 2; ++t)
                af[t] = *(const s16x8*)&Xs[(w * 32 + t * 16 + (lane & 15)) * 40 + (lane >> 4) * 8];
#pragma unroll
            for (int t = 0; t < 8; ++t)
                bfr[t] = *(const s16x8*)&Ms[(t * 16 + (lane & 15)) * 40 + (lane >> 4) * 8];
#pragma unroll
            for (int mf = 0; mf < 2; ++mf)
#pragma unroll
                for (int nf = 0; nf < 8; ++nf)
                    acc[mf][nf] = __builtin_amdgcn_mfma_f32_16x16x32_bf16(
                        af[mf], bfr[nf], acc[mf][nf], 0, 0, 0);
            __syncthreads();
        }
#pragma unroll
        for (int mf = 0; mf < 2; ++mf)
#pragma unroll
            for (int nf = 0; nf < 8; ++nf)
#pragma unroll
                for (int i = 0; i < 4; ++i)
                    psum[mf][i] += tanhf(acc[mf][nf][i] + bc);
    }

#pragma unroll
    for (int mf = 0; mf < 2; ++mf)
#pragma unroll
        for (int i = 0; i < 4; ++i) {
            float v = psum[mf][i];
            v += __shfl_xor(v, 1); v += __shfl_xor(v, 2);
            v += __shfl_xor(v, 4); v += __shfl_xor(v, 8);
            if ((lane & 15) == 0)
                sout[b * 256 + it * 128 + w * 32 + mf * 16 + (lane >> 4) * 4 + i] = v;
        }
}

// al[row] = sum_e sigmoid(gv[row,e] + bv[e]) * wv1[e]   (one wave per row)
__global__ __launch_bounds__(256)
void gv_reduce(const float* __restrict__ gv, const float* __restrict__ bv,
               const float* __restrict__ wv1, float* __restrict__ al)
{
    const int row = blockIdx.x * 4 + (threadIdx.x >> 6);
    const int l = threadIdx.x & 63;
    const float4 v  = *(const float4*)(gv + (size_t)row * 256 + l * 4);
    const float4 bb = *(const float4*)(bv + l * 4);
    const float4 w  = *(const float4*)(wv1 + l * 4);
    float s = w.x / (1.f + expf(-(v.x + bb.x)))
            + w.y / (1.f + expf(-(v.y + bb.y)))
            + w.z / (1.f + expf(-(v.z + bb.z)))
            + w.w / (1.f + expf(-(v.w + bb.w)));
#pragma unroll
    for (int m = 1; m < 64; m <<= 1) s += __shfl_xor(s, m);
    if (l == 0) al[row] = s;
}

// transpose 4 matrices of 256x256 (src[c][d][e] -> dst[c][e][d])
__global__ void transpose256(const float* __restrict__ src, float* __restrict__ dst)
{
    const float* s = src + (size_t)blockIdx.x * 65536;
    float* d = dst + (size_t)blockIdx.x * 65536;
    __shared__ float t[32][33];
    const int tx = threadIdx.x & 31, ty8 = threadIdx.x >> 5;
    for (int bi = 0; bi < 8; ++bi)
        for (int bj = 0; bj < 8; ++bj) {
            __syncthreads();
            for (int r = ty8; r < 32; r += 8)
                t[r][tx] = s[(size_t)(bi * 32 + r) * 256 + bj * 32 + tx];
            __syncthreads();
            for (int r = ty8; r < 32; r += 8)
                d[(size_t)(bj * 32 + r) * 256 + bi * 32 + tx] = t[tx][r];
        }
}

__global__ void softmax256(const float* __restrict__ in, float* __restrict__ out)
{
    __shared__ float red[256];
    const int row = blockIdx.x, t = threadIdx.x;
    const float v = in[(size_t)row * 256 + t];
    red[t] = v; __syncthreads();
    for (int off = 128; off; off >>= 1) {
        if (t < off) red[t] = fmaxf(red[t], red[t + off]);
        __syncthreads();
    }
    const float mx = red[0]; __syncthreads();
    const float e = expf(v - mx);
    red[t] = e; __syncthreads();
    for (int off = 128; off; off >>= 1) {
        if (t < off) red[t] += red[t + off];
        __syncthreads();
    }
    out[(size_t)row * 256 + t] = e / red[0];
}

// new[c,b,d] = sum_l aa[c,b,l] * x[b,l,d]
__global__ void weighted_sum_kernel(const float* __restrict__ aa,
                                    const float* __restrict__ x,
                                    float* __restrict__ outnew)
{
    const int b = blockIdx.x, c = blockIdx.y, d = threadIdx.x;
    __shared__ float w[Ln];
    w[d] = aa[((size_t)c * Bn + b) * Ln + d];
    __syncthreads();
    float acc = 0.f;
    for (int l = 0; l < Ln; ++l)
        acc += w[l] * x[((size_t)b * Ln + l) * Dn + d];
    outnew[((size_t)c * Bn + b) * Dn + d] = acc;
}

// pack conv filter rows (216) into 256x256 fp32 (rows 216+ zero)
__global__ void wpack_fill(const float* __restrict__ w0, const float* __restrict__ w1,
                           const float* __restrict__ w2, const float* __restrict__ w3,
                           float* __restrict__ wp)
{
    const int f = blockIdx.x;
    if (f < 4) {
        const int cnt[4]  = {4096, 9216, 16384, 25600};
        const int boff[4] = {0, 4096, 13312, 29696};
        const float* src = f == 0 ? w0 : f == 1 ? w1 : f == 2 ? w2 : w3;
        for (int i = threadIdx.x; i < cnt[f]; i += blockDim.x)
            wp[boff[f] + i] = src[i];
    } else {
        for (int i = threadIdx.x; i < 65536 - 55296; i += blockDim.x)
            wp[55296 + i] = 0.f;
    }
}

// nwd[b,row] = dot(new[c_of_row, b, :], wpack[row, :])
__global__ __launch_bounds__(256)
void nwd_kernel(const float* __restrict__ nw, const float* __restrict__ wp,
                float* __restrict__ nwd)
{
    const int b = blockIdx.x;
    __shared__ float ns[4][256];
    for (int i = threadIdx.x; i < 1024; i += 256)
        ns[i >> 8][i & 255] = nw[((size_t)((i >> 8) * Bn + b) << 8) + (i & 255)];
    __syncthreads();
    const int row = threadIdx.x;
    if (row < 216) {
        int f, base;
        if (row < 16)       { f = 0; base = 0; }
        else if (row < 52)  { f = 1; base = 16; }
        else if (row < 116) { f = 2; base = 52; }
        else                { f = 3; base = 116; }
        const int fs = f + 2, local = row - base;
        const int c = (local / fs) & 3;
        const float* wr = wp + (size_t)row * 256;
        float acc = 0.f;
        for (int k = 0; k < 256; ++k) acc += ns[c][k] * wr[k];
        nwd[b * 256 + row] = acc;
    }
}

// conv+relu+maxpool via decomposition over a-weighted x rows + new offset
__global__ __launch_bounds__(256)
void conv_combine(const float* __restrict__ xwT, const float* __restrict__ a,
                  const float* __restrict__ nwd, const float* __restrict__ cb,
                  float* __restrict__ pool, int fs, int base, int poff)
{
    const int b = blockIdx.x, tid = threadIdx.x;
    __shared__ float ash[4][256];
    __shared__ float basev[5];
    __shared__ float red[256];
    for (int i = tid; i < 1024; i += 256)
        ash[i >> 8][i & 255] = a[((size_t)((i >> 8) * Bn + b) << 8) + (i & 255)];
    if (tid < fs) {
        float s = cb[tid];
        for (int c = 0; c < 4; ++c)
            for (int kh = 0; kh < fs; ++kh)
                s += nwd[b * 256 + base + (tid * 4 + c) * fs + kh];
        basev[tid] = s;
    }
    __syncthreads();
    const int ni = Ln - fs + 1;
    const float* xb = xwT + ((size_t)b << 16);
    for (int o = 0; o < fs; ++o) {
        float best = 0.f;
        if (tid < ni) {
            float acc = basev[o];
            for (int c = 0; c < 4; ++c)
                for (int kh = 0; kh < fs; ++kh) {
                    const int row = base + (o * 4 + c) * fs + kh;
                    acc += ash[c][tid + kh] * xb[(row << 8) + tid + kh];
                }
            best = fmaxf(acc, 0.f);
        }
        red[tid] = best; __syncthreads();
        for (int off = 128; off; off >>= 1) {
            if (tid < off) red[tid] = fmaxf(red[tid], red[tid + off]);
            __syncthreads();
        }
        if (tid == 0) pool[b * 14 + poff + o] = red[0];
        __syncthreads();
    }
}

__global__ void fc_kernel(const float* __restrict__ pool, const float* __restrict__ fw,
                          const float* __restrict__ fb, float* __restrict__ out)
{
    const int i = threadIdx.x;           // 256 = B*OUT
    const int b = i >> 1, o = i & 1;
    float acc = fb[o];
#pragma unroll
    for (int f = 0; f < 14; ++f) acc += pool[b * 14 + f] * fw[o * 14 + f];
    out[i] = acc;
}

// ---------------------------------------------------------------------------
extern "C" void kernel_launch(void* const* d_in, const int* in_sizes, int n_in,
                              void* d_out, int out_size, void* d_ws, size_t ws_size,
                              hipStream_t stream)
{
    const int*   utt    = (const int*)  d_in[0];
    const float* emb    = (const float*)d_in[2];
    const float* w_ih0  = (const float*)d_in[3];
    const float* w_hh0  = (const float*)d_in[4];
    const float* b_ih0  = (const float*)d_in[5];
    const float* b_hh0  = (const float*)d_in[6];
    const float* w_ih1  = (const float*)d_in[7];
    const float* w_hh1  = (const float*)d_in[8];
    const float* b_ih1  = (const float*)d_in[9];
    const float* b_hh1  = (const float*)d_in[10];
    const float* att_w  = (const float*)d_in[11];
    const float* att_b  = (const float*)d_in[12];
    const float* att_wv2= (const float*)d_in[13];
    const float* att_bv = (const float*)d_in[14];
    const float* att_wv1= (const float*)d_in[15];
    const float* fc_w   = (const float*)d_in[16];
    const float* fc_b   = (const float*)d_in[17];
    const float* cw[4] = {(const float*)d_in[18], (const float*)d_in[20],
                          (const float*)d_in[22], (const float*)d_in[24]};
    const float* cb[4] = {(const float*)d_in[19], (const float*)d_in[21],
                          (const float*)d_in[23], (const float*)d_in[25]};

    float* ws = (float*)d_ws;
    bf16*  GX   = (bf16*)ws;           // 32768*768 bf16 = 12,582,912 f32 slots
    float* H1   = ws + 12582912;       // 8,388,608 f ; later aliased as MATc
    float* H2   = H1 + 8388608;        // 8,388,608 f
    float* WT   = H2 + 8388608;        //   262,144 f (att_wT, then wv2T)
    float* WP   = WT + 262144;         //    65,536 f
    float* S    = WP + 65536;          //   131,072 f
    float* Aa   = S + 131072;
    float* AL   = Aa + 131072;
    float* AAa  = AL + 131072;
    float* NEW_ = AAa + 131072;
    float* NWD  = NEW_ + 131072;       //    32,768 f
    float* POOL = NWD + 32768;         //     1,792 f
    float* MATc = H1;                  // alias (H1 dead after layer-1 gemm)
    float* GV   = ws;                  // alias gx region (dead after scan 2)
    float* XWT  = ws;                  // alias (GV dead after gv_reduce)

    // layer 0 + scan
    gemm_mfma<bf16, true, 0><<<dim3(6, 256), 256, 0, stream>>>(
        emb, w_ih0, b_ih0, GX, utt, BLn, 768, En);
    gru_scan_mfma<<<dim3(Bn / 16, 2), 512, 0, stream>>>(GX, w_hh0, b_hh0, H1);
    // layer 1 + scan
    gemm_mfma<bf16, false, 0><<<dim3(6, 256), 256, 0, stream>>>(
        H1, w_ih1, b_ih1, GX, nullptr, BLn, 768, Dn);
    gru_scan_mfma<<<dim3(Bn / 16, 2), 512, 0, stream>>>(GX, w_hh1, b_hh1, H2);

    // scalar attention: mat_c = x @ att_w[c], fused tanh-sum scores
    transpose256<<<4, 256, 0, stream>>>(att_w, WT);
    for (int c = 0; c < 4; ++c) {
        gemm_mfma<float, false, 0><<<dim3(2, 256), 256, 0, stream>>>(
            H2, WT + (size_t)c * 65536, nullptr, MATc, nullptr, BLn, Dn, Dn);
        attn_score_mfma<<<dim3(2, Bn), 256, 0, stream>>>(
            H2, MATc, att_b, c, S + (size_t)c * 32768);
    }
    softmax256<<<Cn * Bn, 256, 0, stream>>>(S, Aa);

    // vector attention: gv = x @ wv2[c], reduce with sigmoid*wv1
    transpose256<<<4, 256, 0, stream>>>(att_wv2, WT);
    for (int c = 0; c < 4; ++c) {
        gemm_mfma<float, false, 0><<<dim3(2, 256), 256, 0, stream>>>(
            H2, WT + (size_t)c * 65536, nullptr, GV, nullptr, BLn, Dn, Dn);
        gv_reduce<<<BLn / 4, 256, 0, stream>>>(
            GV, att_bv + c * Dn, att_wv1 + c * Dn, AL + (size_t)c * BLn);
    }
    softmax256<<<Cn * Bn, 256, 0, stream>>>(AL, AAa);
    weighted_sum_kernel<<<dim3(Bn, Cn), 256, 0, stream>>>(AAa, H2, NEW_);

    // conv stage via xw GEMM decomposition (Cf never materialized)
    wpack_fill<<<5, 256, 0, stream>>>(cw[0], cw[1], cw[2], cw[3], WP);
    gemm_mfma<float, false, 1><<<dim3(2, 256), 256, 0, stream>>>(
        H2, WP, nullptr, XWT, nullptr, BLn, Dn, Dn);
    nwd_kernel<<<Bn, 256, 0, stream>>>(NEW_, WP, NWD);

    const int baserow[4] = {0, 16, 52, 116};
    const int poff[4]    = {0, 2, 5, 9};
    for (int f = 0; f < 4; ++f)
        conv_combine<<<Bn, 256, 0, stream>>>(XWT, Aa, NWD, cb[f], POOL, f + 2, baserow[f], poff[f]);

    fc_kernel<<<1, 256, 0, stream>>>(POOL, fc_w, fc_b, (float*)d_out);
}

// Round 8
// 1396.027 us; speedup vs baseline: 1.3625x; 1.3625x over previous
//
#include <hip/hip_runtime.h>
#include <hip/hip_bf16.h>
#include <hip/hip_fp16.h>

#define Bn  128
#define Ln  256
#define En  300
#define Hn  128
#define Cn  4
#define Dn  256     // 2H
#define G3n 384     // 3H
#define BLn (Bn * Ln)   // 32768

typedef __hip_bfloat16 bf16;
typedef short s16x8 __attribute__((ext_vector_type(8)));
typedef float f32x4 __attribute__((ext_vector_type(4)));
typedef _Float16 h16x2 __attribute__((ext_vector_type(2)));

__device__ __forceinline__ float ldf(const float* p) { return *p; }
__device__ __forceinline__ float ldf(const bf16* p)  { return __bfloat162float(*p); }
__device__ __forceinline__ void stf(float* p, float v) { *p = v; }
__device__ __forceinline__ void stf(bf16* p, float v)  { *p = __float2bfloat16(v); }

__device__ __forceinline__ ushort f2bf(float f) {
    bf16 h = __float2bfloat16(f);
    return *reinterpret_cast<ushort*>(&h);
}

#if __has_builtin(__builtin_amdgcn_fdot2)
__device__ __forceinline__ float dot2f(h16x2 w, h16x2 h, float c) {
    return __builtin_amdgcn_fdot2(w, h, c, false);
}
#else
__device__ __forceinline__ float dot2f(h16x2 w, h16x2 h, float c) {
    return fmaf((float)w[0], (float)h[0], fmaf((float)w[1], (float)h[1], c));
}
#endif

// ---------------------------------------------------------------------------
// MFMA bf16 GEMM: C[M,N] = A[M,K] * W^T + bias   (W is (N,K) row-major)
//   GATHER: A row m = A[gidx[m]*K ..]    SM==1: store C[(m>>8),n,(m&255)]
// 128x128 tile, 4 waves (2x2 of 64x64), BK=32, LDS rows padded to 40 bf16.
// ---------------------------------------------------------------------------
template<class OT, bool GATHER, int SM>
__global__ __launch_bounds__(256)
void gemm_mfma(const float* __restrict__ A, const float* __restrict__ W,
               const float* __restrict__ bias, OT* __restrict__ Cout,
               const int* __restrict__ gidx, int M, int N, int K)
{
    __shared__ ushort Asm[128 * 40];
    __shared__ ushort Bsm[128 * 40];
    const int bm = blockIdx.y * 128, bn = blockIdx.x * 128;
    const int tid = threadIdx.x;
    const int lane = tid & 63, w = tid >> 6, wr = w >> 1, wc = w & 1;

    const float* arow[4];
    const float* brow[4];
#pragma unroll
    for (int u = 0; u < 4; ++u) {
        const int idx = tid + u * 256;
        const int m = idx >> 3;
        arow[u] = A + (size_t)(GATHER ? gidx[bm + m] : (bm + m)) * K;
        brow[u] = W + (size_t)(bn + m) * K;
    }

    f32x4 acc[4][4] = {};
    const int nkt = (K + 31) >> 5;
    for (int kt = 0; kt < nkt; ++kt) {
        const int k0 = kt << 5;
#pragma unroll
        for (int u = 0; u < 4; ++u) {
            const int idx = tid + u * 256;
            const int m = idx >> 3, kq = idx & 7;
            const int kb = k0 + kq * 4;
            float4 v, q;
            if (kb + 4 <= K) {
                v = *(const float4*)(arow[u] + kb);
                q = *(const float4*)(brow[u] + kb);
            } else {
                v.x = kb + 0 < K ? arow[u][kb + 0] : 0.f;
                v.y = kb + 1 < K ? arow[u][kb + 1] : 0.f;
                v.z = kb + 2 < K ? arow[u][kb + 2] : 0.f;
                v.w = kb + 3 < K ? arow[u][kb + 3] : 0.f;
                q.x = kb + 0 < K ? brow[u][kb + 0] : 0.f;
                q.y = kb + 1 < K ? brow[u][kb + 1] : 0.f;
                q.z = kb + 2 < K ? brow[u][kb + 2] : 0.f;
                q.w = kb + 3 < K ? brow[u][kb + 3] : 0.f;
            }
            *(ushort4*)&Asm[m * 40 + kq * 4] =
                make_ushort4(f2bf(v.x), f2bf(v.y), f2bf(v.z), f2bf(v.w));
            *(ushort4*)&Bsm[m * 40 + kq * 4] =
                make_ushort4(f2bf(q.x), f2bf(q.y), f2bf(q.z), f2bf(q.w));
        }
        __syncthreads();
        s16x8 af[4], bfr[4];
#pragma unroll
        for (int t = 0; t < 4; ++t) {
            af[t]  = *(const s16x8*)&Asm[(wr * 64 + t * 16 + (lane & 15)) * 40 + (lane >> 4) * 8];
            bfr[t] = *(const s16x8*)&Bsm[(wc * 64 + t * 16 + (lane & 15)) * 40 + (lane >> 4) * 8];
        }
#pragma unroll
        for (int mf = 0; mf < 4; ++mf)
#pragma unroll
            for (int nf = 0; nf < 4; ++nf)
                acc[mf][nf] = __builtin_amdgcn_mfma_f32_16x16x32_bf16(
                    af[mf], bfr[nf], acc[mf][nf], 0, 0, 0);
        __syncthreads();
    }

#pragma unroll
    for (int mf = 0; mf < 4; ++mf)
#pragma unroll
        for (int nf = 0; nf < 4; ++nf) {
            const int col = bn + wc * 64 + nf * 16 + (lane & 15);
            const float bv_ = bias ? bias[col] : 0.f;
#pragma unroll
            for (int i = 0; i < 4; ++i) {
                const int row = bm + wr * 64 + mf * 16 + (lane >> 4) * 4 + i;
                const float v = acc[mf][nf][i] + bv_;
                if (SM == 1)
                    stf(&Cout[((size_t)(row >> 8) * N + col) * 256 + (row & 255)], v);
                else
                    stf(&Cout[(size_t)row * N + col], v);
            }
        }
}

// ---------------------------------------------------------------------------
// GRU scan v5: LDS-resident f16 weights + v_dot2_f32_f16.
// Grid = (B, 2) -> 256 blocks, one CU each (fixes round-7's 16-block / 1.5%
// occupancy collapse). 384 threads = one gate row each. Weights packed as
// 64 x 384 f16-pairs in LDS (98.3KB, loaded once -- kills the L2 re-stream
// that bounded rounds 3/5/6 at 340-900us; LDS reads are 2-way bank-aliased
// = free). h state fp32 + f16-pair mirror for the dot2 operand. 4 partial
// accumulators break the 64-dot2 dependence chain. gx prefetched 2 ahead.
// ---------------------------------------------------------------------------
__global__ __launch_bounds__(384, 1)
void gru_scan_lds(const bf16* __restrict__ gx, const float* __restrict__ w_hh,
                  const float* __restrict__ b_hh, float* __restrict__ out)
{
    const int b = blockIdx.x, dir = blockIdx.y;
    const int r = threadIdx.x;               // gate row 0..383
    __shared__ h16x2 wp[64][384];            // [k/2][r], 98304 B
    __shared__ h16x2 hp[64];                 // h as f16 pairs
    __shared__ float h_sh[128];
    __shared__ float rs[128], zs[128], gxn[128], ghn[128];

    // stage weights once: flat over (r,k2); consecutive threads -> consecutive
    // float2 -> coalesced 8B loads from L2
    const float* wbase = w_hh + (size_t)dir * G3n * Hn;
    for (int idx = r; idx < G3n * 64; idx += 384) {
        const int rr = idx >> 6, k2 = idx & 63;
        const float2 v = *(const float2*)(wbase + rr * Hn + 2 * k2);
        h16x2 p; p[0] = (_Float16)v.x; p[1] = (_Float16)v.y;
        wp[k2][rr] = p;
    }
    if (r < 64) { h16x2 z; z[0] = (_Float16)0.f; z[1] = (_Float16)0.f; hp[r] = z; }
    if (r < 128) h_sh[r] = 0.f;
    const float bh = b_hh[dir * G3n + r];
    __syncthreads();

    const size_t g0 = (size_t)b * Ln * 768 + dir * G3n + r
                      + (dir ? (size_t)(Ln - 1) * 768 : 0);
    const long gstep = dir ? -768L : 768L;
    float gcur = ldf(&gx[g0]);
    float gnx  = ldf(&gx[g0 + gstep]);

    for (int s = 0; s < Ln; ++s) {
        const int t = dir ? (Ln - 1 - s) : s;
        float gn2 = 0.f;
        if (s + 2 < Ln) gn2 = ldf(&gx[g0 + (long)(s + 2) * gstep]);

        float a0 = 0.f, a1 = 0.f, a2 = 0.f, a3 = 0.f;
#pragma unroll
        for (int i = 0; i < 64; i += 4) {
            a0 = dot2f(wp[i + 0][r], hp[i + 0], a0);
            a1 = dot2f(wp[i + 1][r], hp[i + 1], a1);
            a2 = dot2f(wp[i + 2][r], hp[i + 2], a2);
            a3 = dot2f(wp[i + 3][r], hp[i + 3], a3);
        }
        const float accb = (a0 + a1) + (a2 + a3) + bh;

        if (r < 128)      rs[r]        = 1.f / (1.f + expf(-(gcur + accb)));
        else if (r < 256) zs[r - 128]  = 1.f / (1.f + expf(-(gcur + accb)));
        else { gxn[r - 256] = gcur; ghn[r - 256] = accb; }
        __syncthreads();

        if (r < 64) {
            const int j0 = 2 * r, j1 = j0 + 1;
            const float nn0 = tanhf(gxn[j0] + rs[j0] * ghn[j0]);
            const float nn1 = tanhf(gxn[j1] + rs[j1] * ghn[j1]);
            const float h0 = (1.f - zs[j0]) * nn0 + zs[j0] * h_sh[j0];
            const float h1 = (1.f - zs[j1]) * nn1 + zs[j1] * h_sh[j1];
            h_sh[j0] = h0; h_sh[j1] = h1;
            h16x2 p; p[0] = (_Float16)h0; p[1] = (_Float16)h1;
            hp[r] = p;
            *(float2*)&out[((size_t)b * Ln + t) * Dn + dir * Hn + j0] =
                make_float2(h0, h1);
        }
        __syncthreads();
        gcur = gnx;
        gnx  = gn2;
    }
}

// ---------------------------------------------------------------------------
// attn score, MFMA: s[b,i] = sum_j tanh( x_b[i,:]·mat_b[j,:] + att_b[c] )
// ---------------------------------------------------------------------------
__global__ __launch_bounds__(256)
void attn_score_mfma(const float* __restrict__ x, const float* __restrict__ matc,
                     const float* __restrict__ attb, int c, float* __restrict__ sout)
{
    const int it = blockIdx.x, b = blockIdx.y;
    const float* A  = x    + ((size_t)b * 256 + it * 128) * 256;
    const float* Bm = matc + (size_t)b * 65536;
    __shared__ ushort Xs[128 * 40];
    __shared__ ushort Ms[128 * 40];
    const int tid = threadIdx.x, lane = tid & 63, w = tid >> 6;
    const float bc = attb[c];
    float psum[2][4] = {};

    for (int jt = 0; jt < 2; ++jt) {
        f32x4 acc[2][8] = {};
        for (int kt = 0; kt < 8; ++kt) {
            const int k0 = kt << 5;
#pragma unroll
            for (int u = 0; u < 4; ++u) {
                const int idx = tid + u * 256;
                const int m = idx >> 3, kq = idx & 7;
                const float4 v = *(const float4*)(A + (size_t)m * 256 + k0 + kq * 4);
                const float4 q = *(const float4*)(Bm + (size_t)(jt * 128 + m) * 256 + k0 + kq * 4);
                *(ushort4*)&Xs[m * 40 + kq * 4] =
                    make_ushort4(f2bf(v.x), f2bf(v.y), f2bf(v.z), f2bf(v.w));
                *(ushort4*)&Ms[m * 40 + kq * 4] =
                    make_ushort4(f2bf(q.x), f2bf(q.y), f2bf(q.z), f2bf(q.w));
            }
            __syncthreads();
            s16x8 af[2], bfr[8];
#pragma unroll
            for (int t = 0; t < 2; ++t)
                af[t] = *(const s16x8*)&Xs[(w * 32 + t * 16 + (lane & 15)) * 40 + (lane >> 4) * 8];
#pragma unroll
            for (int t = 0; t < 8; ++t)
                bfr[t] = *(const s16x8*)&Ms[(t * 16 + (lane & 15)) * 40 + (lane >> 4) * 8];
#pragma unroll
            for (int mf = 0; mf < 2; ++mf)
#pragma unroll
                for (int nf = 0; nf < 8; ++nf)
                    acc[mf][nf] = __builtin_amdgcn_mfma_f32_16x16x32_bf16(
                        af[mf], bfr[nf], acc[mf][nf], 0, 0, 0);
            __syncthreads();
        }
#pragma unroll
        for (int mf = 0; mf < 2; ++mf)
#pragma unroll
            for (int nf = 0; nf < 8; ++nf)
#pragma unroll
                for (int i = 0; i < 4; ++i)
                    psum[mf][i] += tanhf(acc[mf][nf][i] + bc);
    }

#pragma unroll
    for (int mf = 0; mf < 2; ++mf)
#pragma unroll
        for (int i = 0; i < 4; ++i) {
            float v = psum[mf][i];
            v += __shfl_xor(v, 1); v += __shfl_xor(v, 2);
            v += __shfl_xor(v, 4); v += __shfl_xor(v, 8);
            if ((lane & 15) == 0)
                sout[b * 256 + it * 128 + w * 32 + mf * 16 + (lane >> 4) * 4 + i] = v;
        }
}

// al[row] = sum_e sigmoid(gv[row,e] + bv[e]) * wv1[e]   (one wave per row)
__global__ __launch_bounds__(256)
void gv_reduce(const float* __restrict__ gv, const float* __restrict__ bv,
               const float* __restrict__ wv1, float* __restrict__ al)
{
    const int row = blockIdx.x * 4 + (threadIdx.x >> 6);
    const int l = threadIdx.x & 63;
    const float4 v  = *(const float4*)(gv + (size_t)row * 256 + l * 4);
    const float4 bb = *(const float4*)(bv + l * 4);
    const float4 w  = *(const float4*)(wv1 + l * 4);
    float s = w.x / (1.f + expf(-(v.x + bb.x)))
            + w.y / (1.f + expf(-(v.y + bb.y)))
            + w.z / (1.f + expf(-(v.z + bb.z)))
            + w.w / (1.f + expf(-(v.w + bb.w)));
#pragma unroll
    for (int m = 1; m < 64; m <<= 1) s += __shfl_xor(s, m);
    if (l == 0) al[row] = s;
}

// transpose 4 matrices of 256x256 (src[c][d][e] -> dst[c][e][d])
__global__ void transpose256(const float* __restrict__ src, float* __restrict__ dst)
{
    const float* s = src + (size_t)blockIdx.x * 65536;
    float* d = dst + (size_t)blockIdx.x * 65536;
    __shared__ float t[32][33];
    const int tx = threadIdx.x & 31, ty8 = threadIdx.x >> 5;
    for (int bi = 0; bi < 8; ++bi)
        for (int bj = 0; bj < 8; ++bj) {
            __syncthreads();
            for (int r = ty8; r < 32; r += 8)
                t[r][tx] = s[(size_t)(bi * 32 + r) * 256 + bj * 32 + tx];
            __syncthreads();
            for (int r = ty8; r < 32; r += 8)
                d[(size_t)(bj * 32 + r) * 256 + bi * 32 + tx] = t[tx][r];
        }
}

__global__ void softmax256(const float* __restrict__ in, float* __restrict__ out)
{
    __shared__ float red[256];
    const int row = blockIdx.x, t = threadIdx.x;
    const float v = in[(size_t)row * 256 + t];
    red[t] = v; __syncthreads();
    for (int off = 128; off; off >>= 1) {
        if (t < off) red[t] = fmaxf(red[t], red[t + off]);
        __syncthreads();
    }
    const float mx = red[0]; __syncthreads();
    const float e = expf(v - mx);
    red[t] = e; __syncthreads();
    for (int off = 128; off; off >>= 1) {
        if (t < off) red[t] += red[t + off];
        __syncthreads();
    }
    out[(size_t)row * 256 + t] = e / red[0];
}

// new[c,b,d] = sum_l aa[c,b,l] * x[b,l,d]
__global__ void weighted_sum_kernel(const float* __restrict__ aa,
                                    const float* __restrict__ x,
                                    float* __restrict__ outnew)
{
    const int b = blockIdx.x, c = blockIdx.y, d = threadIdx.x;
    __shared__ float w[Ln];
    w[d] = aa[((size_t)c * Bn + b) * Ln + d];
    __syncthreads();
    float acc = 0.f;
    for (int l = 0; l < Ln; ++l)
        acc += w[l] * x[((size_t)b * Ln + l) * Dn + d];
    outnew[((size_t)c * Bn + b) * Dn + d] = acc;
}

// pack conv filter rows (216) into 256x256 fp32 (rows 216+ zero)
__global__ void wpack_fill(const float* __restrict__ w0, const float* __restrict__ w1,
                           const float* __restrict__ w2, const float* __restrict__ w3,
                           float* __restrict__ wp)
{
    const int f = blockIdx.x;
    if (f < 4) {
        const int cnt[4]  = {4096, 9216, 16384, 25600};
        const int boff[4] = {0, 4096, 13312, 29696};
        const float* src = f == 0 ? w0 : f == 1 ? w1 : f == 2 ? w2 : w3;
        for (int i = threadIdx.x; i < cnt[f]; i += blockDim.x)
            wp[boff[f] + i] = src[i];
    } else {
        for (int i = threadIdx.x; i < 65536 - 55296; i += blockDim.x)
            wp[55296 + i] = 0.f;
    }
}

// nwd[b,row] = dot(new[c_of_row, b, :], wpack[row, :])
__global__ __launch_bounds__(256)
void nwd_kernel(const float* __restrict__ nw, const float* __restrict__ wp,
                float* __restrict__ nwd)
{
    const int b = blockIdx.x;
    __shared__ float ns[4][256];
    for (int i = threadIdx.x; i < 1024; i += 256)
        ns[i >> 8][i & 255] = nw[((size_t)((i >> 8) * Bn + b) << 8) + (i & 255)];
    __syncthreads();
    const int row = threadIdx.x;
    if (row < 216) {
        int f, base;
        if (row < 16)       { f = 0; base = 0; }
        else if (row < 52)  { f = 1; base = 16; }
        else if (row < 116) { f = 2; base = 52; }
        else                { f = 3; base = 116; }
        const int fs = f + 2, local = row - base;
        const int c = (local / fs) & 3;
        const float* wr = wp + (size_t)row * 256;
        float acc = 0.f;
        for (int k = 0; k < 256; ++k) acc += ns[c][k] * wr[k];
        nwd[b * 256 + row] = acc;
    }
}

// conv+relu+maxpool via decomposition over a-weighted x rows + new offset
__global__ __launch_bounds__(256)
void conv_combine(const float* __restrict__ xwT, const float* __restrict__ a,
                  const float* __restrict__ nwd, const float* __restrict__ cb,
                  float* __restrict__ pool, int fs, int base, int poff)
{
    const int b = blockIdx.x, tid = threadIdx.x;
    __shared__ float ash[4][256];
    __shared__ float basev[5];
    __shared__ float red[256];
    for (int i = tid; i < 1024; i += 256)
        ash[i >> 8][i & 255] = a[((size_t)((i >> 8) * Bn + b) << 8) + (i & 255)];
    if (tid < fs) {
        float s = cb[tid];
        for (int c = 0; c < 4; ++c)
            for (int kh = 0; kh < fs; ++kh)
                s += nwd[b * 256 + base + (tid * 4 + c) * fs + kh];
        basev[tid] = s;
    }
    __syncthreads();
    const int ni = Ln - fs + 1;
    const float* xb = xwT + ((size_t)b << 16);
    for (int o = 0; o < fs; ++o) {
        float best = 0.f;
        if (tid < ni) {
            float acc = basev[o];
            for (int c = 0; c < 4; ++c)
                for (int kh = 0; kh < fs; ++kh) {
                    const int row = base + (o * 4 + c) * fs + kh;
                    acc += ash[c][tid + kh] * xb[(row << 8) + tid + kh];
                }
            best = fmaxf(acc, 0.f);
        }
        red[tid] = best; __syncthreads();
        for (int off = 128; off; off >>= 1) {
            if (tid < off) red[tid] = fmaxf(red[tid], red[tid + off]);
            __syncthreads();
        }
        if (tid == 0) pool[b * 14 + poff + o] = red[0];
        __syncthreads();
    }
}

__global__ void fc_kernel(const float* __restrict__ pool, const float* __restrict__ fw,
                          const float* __restrict__ fb, float* __restrict__ out)
{
    const int i = threadIdx.x;           // 256 = B*OUT
    const int b = i >> 1, o = i & 1;
    float acc = fb[o];
#pragma unroll
    for (int f = 0; f < 14; ++f) acc += pool[b * 14 + f] * fw[o * 14 + f];
    out[i] = acc;
}

// ---------------------------------------------------------------------------
extern "C" void kernel_launch(void* const* d_in, const int* in_sizes, int n_in,
                              void* d_out, int out_size, void* d_ws, size_t ws_size,
                              hipStream_t stream)
{
    const int*   utt    = (const int*)  d_in[0];
    const float* emb    = (const float*)d_in[2];
    const float* w_ih0  = (const float*)d_in[3];
    const float* w_hh0  = (const float*)d_in[4];
    const float* b_ih0  = (const float*)d_in[5];
    const float* b_hh0  = (const float*)d_in[6];
    const float* w_ih1  = (const float*)d_in[7];
    const float* w_hh1  = (const float*)d_in[8];
    const float* b_ih1  = (const float*)d_in[9];
    const float* b_hh1  = (const float*)d_in[10];
    const float* att_w  = (const float*)d_in[11];
    const float* att_b  = (const float*)d_in[12];
    const float* att_wv2= (const float*)d_in[13];
    const float* att_bv = (const float*)d_in[14];
    const float* att_wv1= (const float*)d_in[15];
    const float* fc_w   = (const float*)d_in[16];
    const float* fc_b   = (const float*)d_in[17];
    const float* cw[4] = {(const float*)d_in[18], (const float*)d_in[20],
                          (const float*)d_in[22], (const float*)d_in[24]};
    const float* cb[4] = {(const float*)d_in[19], (const float*)d_in[21],
                          (const float*)d_in[23], (const float*)d_in[25]};

    float* ws = (float*)d_ws;
    bf16*  GX   = (bf16*)ws;           // 32768*768 bf16 = 12,582,912 f32 slots
    float* H1   = ws + 12582912;       // 8,388,608 f ; later aliased as MATc
    float* H2   = H1 + 8388608;        // 8,388,608 f
    float* WT   = H2 + 8388608;        //   262,144 f (att_wT, then wv2T)
    float* WP   = WT + 262144;         //    65,536 f
    float* S    = WP + 65536;          //   131,072 f
    float* Aa   = S + 131072;
    float* AL   = Aa + 131072;
    float* AAa  = AL + 131072;
    float* NEW_ = AAa + 131072;
    float* NWD  = NEW_ + 131072;       //    32,768 f
    float* POOL = NWD + 32768;         //     1,792 f
    float* MATc = H1;                  // alias (H1 dead after layer-1 gemm)
    float* GV   = ws;                  // alias gx region (dead after scan 2)
    float* XWT  = ws;                  // alias (GV dead after gv_reduce)

    // layer 0 + scan
    gemm_mfma<bf16, true, 0><<<dim3(6, 256), 256, 0, stream>>>(
        emb, w_ih0, b_ih0, GX, utt, BLn, 768, En);
    gru_scan_lds<<<dim3(Bn, 2), 384, 0, stream>>>(GX, w_hh0, b_hh0, H1);
    // layer 1 + scan
    gemm_mfma<bf16, false, 0><<<dim3(6, 256), 256, 0, stream>>>(
        H1, w_ih1, b_ih1, GX, nullptr, BLn, 768, Dn);
    gru_scan_lds<<<dim3(Bn, 2), 384, 0, stream>>>(GX, w_hh1, b_hh1, H2);

    // scalar attention: mat_c = x @ att_w[c], fused tanh-sum scores
    transpose256<<<4, 256, 0, stream>>>(att_w, WT);
    for (int c = 0; c < 4; ++c) {
        gemm_mfma<float, false, 0><<<dim3(2, 256), 256, 0, stream>>>(
            H2, WT + (size_t)c * 65536, nullptr, MATc, nullptr, BLn, Dn, Dn);
        attn_score_mfma<<<dim3(2, Bn), 256, 0, stream>>>(
            H2, MATc, att_b, c, S + (size_t)c * 32768);
    }
    softmax256<<<Cn * Bn, 256, 0, stream>>>(S, Aa);

    // vector attention: gv = x @ wv2[c], reduce with sigmoid*wv1
    transpose256<<<4, 256, 0, stream>>>(att_wv2, WT);
    for (int c = 0; c < 4; ++c) {
        gemm_mfma<float, false, 0><<<dim3(2, 256), 256, 0, stream>>>(
            H2, WT + (size_t)c * 65536, nullptr, GV, nullptr, BLn, Dn, Dn);
        gv_reduce<<<BLn / 4, 256, 0, stream>>>(
            GV, att_bv + c * Dn, att_wv1 + c * Dn, AL + (size_t)c * BLn);
    }
    softmax256<<<Cn * Bn, 256, 0, stream>>>(AL, AAa);
    weighted_sum_kernel<<<dim3(Bn, Cn), 256, 0, stream>>>(AAa, H2, NEW_);

    // conv stage via xw GEMM decomposition (Cf never materialized)
    wpack_fill<<<5, 256, 0, stream>>>(cw[0], cw[1], cw[2], cw[3], WP);
    gemm_mfma<float, false, 1><<<dim3(2, 256), 256, 0, stream>>>(
        H2, WP, nullptr, XWT, nullptr, BLn, Dn, Dn);
    nwd_kernel<<<Bn, 256, 0, stream>>>(NEW_, WP, NWD);

    const int baserow[4] = {0, 16, 52, 116};
    const int poff[4]    = {0, 2, 5, 9};
    for (int f = 0; f < 4; ++f)
        conv_combine<<<Bn, 256, 0, stream>>>(XWT, Aa, NWD, cb[f], POOL, f + 2, baserow[f], poff[f]);

    fc_kernel<<<1, 256, 0, stream>>>(POOL, fc_w, fc_b, (float*)d_out);
}

// Round 9
// 1320.426 us; speedup vs baseline: 1.4405x; 1.0573x over previous
//
#include <hip/hip_runtime.h>
#include <hip/hip_bf16.h>
#include <hip/hip_fp16.h>

#define Bn  128
#define Ln  256
#define En  300
#define Hn  128
#define Cn  4
#define Dn  256     // 2H
#define G3n 384     // 3H
#define BLn (Bn * Ln)   // 32768

typedef __hip_bfloat16 bf16;
typedef short s16x8 __attribute__((ext_vector_type(8)));
typedef float f32x4 __attribute__((ext_vector_type(4)));
typedef _Float16 h16x2 __attribute__((ext_vector_type(2)));

__device__ __forceinline__ float ldf(const float* p) { return *p; }
__device__ __forceinline__ float ldf(const bf16* p)  { return __bfloat162float(*p); }
__device__ __forceinline__ void stf(float* p, float v) { *p = v; }
__device__ __forceinline__ void stf(bf16* p, float v)  { *p = __float2bfloat16(v); }

__device__ __forceinline__ ushort f2bf(float f) {
    bf16 h = __float2bfloat16(f);
    return *reinterpret_cast<ushort*>(&h);
}

#if __has_builtin(__builtin_amdgcn_fdot2)
__device__ __forceinline__ float dot2f(h16x2 w, h16x2 h, float c) {
    return __builtin_amdgcn_fdot2(w, h, c, false);
}
#else
__device__ __forceinline__ float dot2f(h16x2 w, h16x2 h, float c) {
    return fmaf((float)w[0], (float)h[0], fmaf((float)w[1], (float)h[1], c));
}
#endif

// ---------------------------------------------------------------------------
// MFMA bf16 GEMM: C[M,N] = A[M,K] * W^T + bias   (W is (N,K) row-major)
//   GATHER: A row m = A[gidx[m]*K ..]    SM==1: store C[(m>>8),n,(m&255)]
// ---------------------------------------------------------------------------
template<class OT, bool GATHER, int SM>
__global__ __launch_bounds__(256)
void gemm_mfma(const float* __restrict__ A, const float* __restrict__ W,
               const float* __restrict__ bias, OT* __restrict__ Cout,
               const int* __restrict__ gidx, int M, int N, int K)
{
    __shared__ ushort Asm[128 * 40];
    __shared__ ushort Bsm[128 * 40];
    const int bm = blockIdx.y * 128, bn = blockIdx.x * 128;
    const int tid = threadIdx.x;
    const int lane = tid & 63, w = tid >> 6, wr = w >> 1, wc = w & 1;

    const float* arow[4];
    const float* brow[4];
#pragma unroll
    for (int u = 0; u < 4; ++u) {
        const int idx = tid + u * 256;
        const int m = idx >> 3;
        arow[u] = A + (size_t)(GATHER ? gidx[bm + m] : (bm + m)) * K;
        brow[u] = W + (size_t)(bn + m) * K;
    }

    f32x4 acc[4][4] = {};
    const int nkt = (K + 31) >> 5;
    for (int kt = 0; kt < nkt; ++kt) {
        const int k0 = kt << 5;
#pragma unroll
        for (int u = 0; u < 4; ++u) {
            const int idx = tid + u * 256;
            const int m = idx >> 3, kq = idx & 7;
            const int kb = k0 + kq * 4;
            float4 v, q;
            if (kb + 4 <= K) {
                v = *(const float4*)(arow[u] + kb);
                q = *(const float4*)(brow[u] + kb);
            } else {
                v.x = kb + 0 < K ? arow[u][kb + 0] : 0.f;
                v.y = kb + 1 < K ? arow[u][kb + 1] : 0.f;
                v.z = kb + 2 < K ? arow[u][kb + 2] : 0.f;
                v.w = kb + 3 < K ? arow[u][kb + 3] : 0.f;
                q.x = kb + 0 < K ? brow[u][kb + 0] : 0.f;
                q.y = kb + 1 < K ? brow[u][kb + 1] : 0.f;
                q.z = kb + 2 < K ? brow[u][kb + 2] : 0.f;
                q.w = kb + 3 < K ? brow[u][kb + 3] : 0.f;
            }
            *(ushort4*)&Asm[m * 40 + kq * 4] =
                make_ushort4(f2bf(v.x), f2bf(v.y), f2bf(v.z), f2bf(v.w));
            *(ushort4*)&Bsm[m * 40 + kq * 4] =
                make_ushort4(f2bf(q.x), f2bf(q.y), f2bf(q.z), f2bf(q.w));
        }
        __syncthreads();
        s16x8 af[4], bfr[4];
#pragma unroll
        for (int t = 0; t < 4; ++t) {
            af[t]  = *(const s16x8*)&Asm[(wr * 64 + t * 16 + (lane & 15)) * 40 + (lane >> 4) * 8];
            bfr[t] = *(const s16x8*)&Bsm[(wc * 64 + t * 16 + (lane & 15)) * 40 + (lane >> 4) * 8];
        }
#pragma unroll
        for (int mf = 0; mf < 4; ++mf)
#pragma unroll
            for (int nf = 0; nf < 4; ++nf)
                acc[mf][nf] = __builtin_amdgcn_mfma_f32_16x16x32_bf16(
                    af[mf], bfr[nf], acc[mf][nf], 0, 0, 0);
        __syncthreads();
    }

#pragma unroll
    for (int mf = 0; mf < 4; ++mf)
#pragma unroll
        for (int nf = 0; nf < 4; ++nf) {
            const int col = bn + wc * 64 + nf * 16 + (lane & 15);
            const float bv_ = bias ? bias[col] : 0.f;
#pragma unroll
            for (int i = 0; i < 4; ++i) {
                const int row = bm + wr * 64 + mf * 16 + (lane >> 4) * 4 + i;
                const float v = acc[mf][nf][i] + bv_;
                if (SM == 1)
                    stf(&Cout[((size_t)(row >> 8) * N + col) * 256 + (row & 255)], v);
                else
                    stf(&Cout[(size_t)row * N + col], v);
            }
        }
}

// ---------------------------------------------------------------------------
// GRU scan v6: VGPR-resident f16 weights + v_dot2_f32_f16.
// Round-8 analysis: scan is LDS-ISSUE bound (64 scalar ds_read/thread/step
// ~ 2200 cyc/step); L2-stream (r3), scratch (r5), LDS (r8) all converge to
// ~340us. Only the register file can feed the FMAs without a load stream.
// Defenses against the r5/r6 demotions: 64 macro-NAMED scalar carriers (no
// array, no punning), each pinned by asm "+v" (opaque redefinition: loads
// cannot be rematerialized past it), and w_hh/out NOT __restrict__ (reload
// after in-loop out-stores would be illegal anyway).
// Thread (p,half) owns rows {p, p+192} x k-half; per step: 8 broadcast
// ds_read_b128 for h + 64 dot2; halves combined via shfl_xor(1).
// ---------------------------------------------------------------------------
#define W32(OP) OP(0)OP(1)OP(2)OP(3)OP(4)OP(5)OP(6)OP(7)OP(8)OP(9)OP(10)OP(11)\
OP(12)OP(13)OP(14)OP(15)OP(16)OP(17)OP(18)OP(19)OP(20)OP(21)OP(22)OP(23)OP(24)\
OP(25)OP(26)OP(27)OP(28)OP(29)OP(30)OP(31)
#define DECL_W(i) float wA##i, wB##i;
#define LOAD_W(i) { \
    const float2 v = *(const float2*)(wAp + 2 * i); \
    h16x2 q; q[0] = (_Float16)v.x; q[1] = (_Float16)v.y; \
    wA##i = __builtin_bit_cast(float, q); \
    const float2 u = *(const float2*)(wBp + 2 * i); \
    h16x2 s2; s2[0] = (_Float16)u.x; s2[1] = (_Float16)u.y; \
    wB##i = __builtin_bit_cast(float, s2); }
#define PIN_W(i) asm volatile("" : "+v"(wA##i), "+v"(wB##i));
#define BCH(x) __builtin_bit_cast(h16x2, x)
#define DOTCHUNK(c, i0, i1, i2, i3) { \
    const float4 hv = *(const float4*)(&hp[hoff + 4 * c]); \
    const h16x2 h0 = BCH(hv.x), h1 = BCH(hv.y), h2 = BCH(hv.z), h3 = BCH(hv.w); \
    a0 = dot2f(BCH(wA##i0), h0, a0); a1 = dot2f(BCH(wA##i1), h1, a1); \
    a2 = dot2f(BCH(wA##i2), h2, a2); a3 = dot2f(BCH(wA##i3), h3, a3); \
    c0 = dot2f(BCH(wB##i0), h0, c0); c1 = dot2f(BCH(wB##i1), h1, c1); \
    c2 = dot2f(BCH(wB##i2), h2, c2); c3 = dot2f(BCH(wB##i3), h3, c3); }

__global__ __launch_bounds__(384, 1)
void gru_scan_reg(const bf16* __restrict__ gx, const float* w_hh,
                  const float* __restrict__ b_hh, float* out)
{
    const int b = blockIdx.x, dir = blockIdx.y;
    const int t = threadIdx.x;
    const int p = t >> 1, half = t & 1;
    const int rA = p, rB = p + 192;
    const int hoff = half * 32;

    __shared__ float h_sh[128];
    __shared__ h16x2 hp[64];
    __shared__ float rs[128], zs[128], gxn[128], ghn[128];

    const float* wAp = w_hh + ((size_t)dir * G3n + rA) * Hn + half * 64;
    const float* wBp = w_hh + ((size_t)dir * G3n + rB) * Hn + half * 64;
    W32(DECL_W)
    W32(LOAD_W)
    W32(PIN_W)

    const int rE = half ? rB : rA;              // row this thread emits
    const float bhA = b_hh[dir * G3n + rA];
    const float bhB = b_hh[dir * G3n + rB];

    if (t < 128) h_sh[t] = 0.f;
    if (t < 64) { h16x2 z; z[0] = (_Float16)0.f; z[1] = (_Float16)0.f; hp[t] = z; }
    __syncthreads();

    const size_t g0 = (size_t)b * Ln * 768 + dir * G3n + rE
                      + (dir ? (size_t)(Ln - 1) * 768 : 0);
    const long gstep = dir ? -768L : 768L;
    float gcur = ldf(&gx[g0]);
    float gnx  = ldf(&gx[g0 + gstep]);

    for (int s = 0; s < Ln; ++s) {
        const int tt = dir ? (Ln - 1 - s) : s;
        float gn2 = 0.f;
        if (s + 2 < Ln) gn2 = ldf(&gx[g0 + (long)(s + 2) * gstep]);

        float a0 = 0.f, a1 = 0.f, a2 = 0.f, a3 = 0.f;
        float c0 = 0.f, c1 = 0.f, c2 = 0.f, c3 = 0.f;
        DOTCHUNK(0,  0,  1,  2,  3)
        DOTCHUNK(1,  4,  5,  6,  7)
        DOTCHUNK(2,  8,  9, 10, 11)
        DOTCHUNK(3, 12, 13, 14, 15)
        DOTCHUNK(4, 16, 17, 18, 19)
        DOTCHUNK(5, 20, 21, 22, 23)
        DOTCHUNK(6, 24, 25, 26, 27)
        DOTCHUNK(7, 28, 29, 30, 31)
        float accA = (a0 + a1) + (a2 + a3);
        float accB = (c0 + c1) + (c2 + c3);
        accA += __shfl_xor(accA, 1);
        accB += __shfl_xor(accB, 1);
        const float acc = half ? (accB + bhB) : (accA + bhA);

        if (rE < 128)      rs[rE]       = 1.f / (1.f + expf(-(gcur + acc)));
        else if (rE < 256) zs[rE - 128] = 1.f / (1.f + expf(-(gcur + acc)));
        else { gxn[rE - 256] = gcur; ghn[rE - 256] = acc; }
        __syncthreads();

        if (t < 64) {
            const int j0 = 2 * t, j1 = j0 + 1;
            const float nn0 = tanhf(gxn[j0] + rs[j0] * ghn[j0]);
            const float nn1 = tanhf(gxn[j1] + rs[j1] * ghn[j1]);
            const float h0 = (1.f - zs[j0]) * nn0 + zs[j0] * h_sh[j0];
            const float h1 = (1.f - zs[j1]) * nn1 + zs[j1] * h_sh[j1];
            h_sh[j0] = h0; h_sh[j1] = h1;
            h16x2 pr; pr[0] = (_Float16)h0; pr[1] = (_Float16)h1;
            hp[t] = pr;
            *(float2*)&out[((size_t)b * Ln + tt) * Dn + dir * Hn + j0] =
                make_float2(h0, h1);
        }
        __syncthreads();
        gcur = gnx; gnx = gn2;
    }
}

// ---------------------------------------------------------------------------
// attn score, MFMA: s[b,i] = sum_j tanh( x_b[i,:]·mat_b[j,:] + att_b[c] )
// ---------------------------------------------------------------------------
__global__ __launch_bounds__(256)
void attn_score_mfma(const float* __restrict__ x, const float* __restrict__ matc,
                     const float* __restrict__ attb, int c, float* __restrict__ sout)
{
    const int it = blockIdx.x, b = blockIdx.y;
    const float* A  = x    + ((size_t)b * 256 + it * 128) * 256;
    const float* Bm = matc + (size_t)b * 65536;
    __shared__ ushort Xs[128 * 40];
    __shared__ ushort Ms[128 * 40];
    const int tid = threadIdx.x, lane = tid & 63, w = tid >> 6;
    const float bc = attb[c];
    float psum[2][4] = {};

    for (int jt = 0; jt < 2; ++jt) {
        f32x4 acc[2][8] = {};
        for (int kt = 0; kt < 8; ++kt) {
            const int k0 = kt << 5;
#pragma unroll
            for (int u = 0; u < 4; ++u) {
                const int idx = tid + u * 256;
                const int m = idx >> 3, kq = idx & 7;
                const float4 v = *(const float4*)(A + (size_t)m * 256 + k0 + kq * 4);
                const float4 q = *(const float4*)(Bm + (size_t)(jt * 128 + m) * 256 + k0 + kq * 4);
                *(ushort4*)&Xs[m * 40 + kq * 4] =
                    make_ushort4(f2bf(v.x), f2bf(v.y), f2bf(v.z), f2bf(v.w));
                *(ushort4*)&Ms[m * 40 + kq * 4] =
                    make_ushort4(f2bf(q.x), f2bf(q.y), f2bf(q.z), f2bf(q.w));
            }
            __syncthreads();
            s16x8 af[2], bfr[8];
#pragma unroll
            for (int t = 0; t < 2; ++t)
                af[t] = *(const s16x8*)&Xs[(w * 32 + t * 16 + (lane & 15)) * 40 + (lane >> 4) * 8];
#pragma unroll
            for (int t = 0; t < 8; ++t)
                bfr[t] = *(const s16x8*)&Ms[(t * 16 + (lane & 15)) * 40 + (lane >> 4) * 8];
#pragma unroll
            for (int mf = 0; mf < 2; ++mf)
#pragma unroll
                for (int nf = 0; nf < 8; ++nf)
                    acc[mf][nf] = __builtin_amdgcn_mfma_f32_16x16x32_bf16(
                        af[mf], bfr[nf], acc[mf][nf], 0, 0, 0);
            __syncthreads();
        }
#pragma unroll
        for (int mf = 0; mf < 2; ++mf)
#pragma unroll
            for (int nf = 0; nf < 8; ++nf)
#pragma unroll
                for (int i = 0; i < 4; ++i)
                    psum[mf][i] += tanhf(acc[mf][nf][i] + bc);
    }

#pragma unroll
    for (int mf = 0; mf < 2; ++mf)
#pragma unroll
        for (int i = 0; i < 4; ++i) {
            float v = psum[mf][i];
            v += __shfl_xor(v, 1); v += __shfl_xor(v, 2);
            v += __shfl_xor(v, 4); v += __shfl_xor(v, 8);
            if ((lane & 15) == 0)
                sout[b * 256 + it * 128 + w * 32 + mf * 16 + (lane >> 4) * 4 + i] = v;
        }
}

// al[row] = sum_e sigmoid(gv[row,e] + bv[e]) * wv1[e]   (one wave per row)
__global__ __launch_bounds__(256)
void gv_reduce(const float* __restrict__ gv, const float* __restrict__ bv,
               const float* __restrict__ wv1, float* __restrict__ al)
{
    const int row = blockIdx.x * 4 + (threadIdx.x >> 6);
    const int l = threadIdx.x & 63;
    const float4 v  = *(const float4*)(gv + (size_t)row * 256 + l * 4);
    const float4 bb = *(const float4*)(bv + l * 4);
    const float4 w  = *(const float4*)(wv1 + l * 4);
    float s = w.x / (1.f + expf(-(v.x + bb.x)))
            + w.y / (1.f + expf(-(v.y + bb.y)))
            + w.z / (1.f + expf(-(v.z + bb.z)))
            + w.w / (1.f + expf(-(v.w + bb.w)));
#pragma unroll
    for (int m = 1; m < 64; m <<= 1) s += __shfl_xor(s, m);
    if (l == 0) al[row] = s;
}

// transpose 4 matrices of 256x256 (src[c][d][e] -> dst[c][e][d])
__global__ void transpose256(const float* __restrict__ src, float* __restrict__ dst)
{
    const float* s = src + (size_t)blockIdx.x * 65536;
    float* d = dst + (size_t)blockIdx.x * 65536;
    __shared__ float t[32][33];
    const int tx = threadIdx.x & 31, ty8 = threadIdx.x >> 5;
    for (int bi = 0; bi < 8; ++bi)
        for (int bj = 0; bj < 8; ++bj) {
            __syncthreads();
            for (int r = ty8; r < 32; r += 8)
                t[r][tx] = s[(size_t)(bi * 32 + r) * 256 + bj * 32 + tx];
            __syncthreads();
            for (int r = ty8; r < 32; r += 8)
                d[(size_t)(bj * 32 + r) * 256 + bi * 32 + tx] = t[tx][r];
        }
}

__global__ void softmax256(const float* __restrict__ in, float* __restrict__ out)
{
    __shared__ float red[256];
    const int row = blockIdx.x, t = threadIdx.x;
    const float v = in[(size_t)row * 256 + t];
    red[t] = v; __syncthreads();
    for (int off = 128; off; off >>= 1) {
        if (t < off) red[t] = fmaxf(red[t], red[t + off]);
        __syncthreads();
    }
    const float mx = red[0]; __syncthreads();
    const float e = expf(v - mx);
    red[t] = e; __syncthreads();
    for (int off = 128; off; off >>= 1) {
        if (t < off) red[t] += red[t + off];
        __syncthreads();
    }
    out[(size_t)row * 256 + t] = e / red[0];
}

// new[c,b,d] = sum_l aa[c,b,l] * x[b,l,d]
__global__ void weighted_sum_kernel(const float* __restrict__ aa,
                                    const float* __restrict__ x,
                                    float* __restrict__ outnew)
{
    const int b = blockIdx.x, c = blockIdx.y, d = threadIdx.x;
    __shared__ float w[Ln];
    w[d] = aa[((size_t)c * Bn + b) * Ln + d];
    __syncthreads();
    float acc = 0.f;
    for (int l = 0; l < Ln; ++l)
        acc += w[l] * x[((size_t)b * Ln + l) * Dn + d];
    outnew[((size_t)c * Bn + b) * Dn + d] = acc;
}

// pack conv filter rows (216) into 256x256 fp32 (rows 216+ zero)
__global__ void wpack_fill(const float* __restrict__ w0, const float* __restrict__ w1,
                           const float* __restrict__ w2, const float* __restrict__ w3,
                           float* __restrict__ wp)
{
    const int f = blockIdx.x;
    if (f < 4) {
        const int cnt[4]  = {4096, 9216, 16384, 25600};
        const int boff[4] = {0, 4096, 13312, 29696};
        const float* src = f == 0 ? w0 : f == 1 ? w1 : f == 2 ? w2 : w3;
        for (int i = threadIdx.x; i < cnt[f]; i += blockDim.x)
            wp[boff[f] + i] = src[i];
    } else {
        for (int i = threadIdx.x; i < 65536 - 55296; i += blockDim.x)
            wp[55296 + i] = 0.f;
    }
}

// nwd[b,row] = dot(new[c_of_row, b, :], wpack[row, :])
__global__ __launch_bounds__(256)
void nwd_kernel(const float* __restrict__ nw, const float* __restrict__ wp,
                float* __restrict__ nwd)
{
    const int b = blockIdx.x;
    __shared__ float ns[4][256];
    for (int i = threadIdx.x; i < 1024; i += 256)
        ns[i >> 8][i & 255] = nw[((size_t)((i >> 8) * Bn + b) << 8) + (i & 255)];
    __syncthreads();
    const int row = threadIdx.x;
    if (row < 216) {
        int f, base;
        if (row < 16)       { f = 0; base = 0; }
        else if (row < 52)  { f = 1; base = 16; }
        else if (row < 116) { f = 2; base = 52; }
        else                { f = 3; base = 116; }
        const int fs = f + 2, local = row - base;
        const int c = (local / fs) & 3;
        const float* wr = wp + (size_t)row * 256;
        float acc = 0.f;
        for (int k = 0; k < 256; ++k) acc += ns[c][k] * wr[k];
        nwd[b * 256 + row] = acc;
    }
}

// conv+relu+maxpool via decomposition over a-weighted x rows + new offset
__global__ __launch_bounds__(256)
void conv_combine(const float* __restrict__ xwT, const float* __restrict__ a,
                  const float* __restrict__ nwd, const float* __restrict__ cb,
                  float* __restrict__ pool, int fs, int base, int poff)
{
    const int b = blockIdx.x, tid = threadIdx.x;
    __shared__ float ash[4][256];
    __shared__ float basev[5];
    __shared__ float red[256];
    for (int i = tid; i < 1024; i += 256)
        ash[i >> 8][i & 255] = a[((size_t)((i >> 8) * Bn + b) << 8) + (i & 255)];
    if (tid < fs) {
        float s = cb[tid];
        for (int c = 0; c < 4; ++c)
            for (int kh = 0; kh < fs; ++kh)
                s += nwd[b * 256 + base + (tid * 4 + c) * fs + kh];
        basev[tid] = s;
    }
    __syncthreads();
    const int ni = Ln - fs + 1;
    const float* xb = xwT + ((size_t)b << 16);
    for (int o = 0; o < fs; ++o) {
        float best = 0.f;
        if (tid < ni) {
            float acc = basev[o];
            for (int c = 0; c < 4; ++c)
                for (int kh = 0; kh < fs; ++kh) {
                    const int row = base + (o * 4 + c) * fs + kh;
                    acc += ash[c][tid + kh] * xb[(row << 8) + tid + kh];
                }
            best = fmaxf(acc, 0.f);
        }
        red[tid] = best; __syncthreads();
        for (int off = 128; off; off >>= 1) {
            if (tid < off) red[tid] = fmaxf(red[tid], red[tid + off]);
            __syncthreads();
        }
        if (tid == 0) pool[b * 14 + poff + o] = red[0];
        __syncthreads();
    }
}

__global__ void fc_kernel(const float* __restrict__ pool, const float* __restrict__ fw,
                          const float* __restrict__ fb, float* __restrict__ out)
{
    const int i = threadIdx.x;           // 256 = B*OUT
    const int b = i >> 1, o = i & 1;
    float acc = fb[o];
#pragma unroll
    for (int f = 0; f < 14; ++f) acc += pool[b * 14 + f] * fw[o * 14 + f];
    out[i] = acc;
}

// ---------------------------------------------------------------------------
extern "C" void kernel_launch(void* const* d_in, const int* in_sizes, int n_in,
                              void* d_out, int out_size, void* d_ws, size_t ws_size,
                              hipStream_t stream)
{
    const int*   utt    = (const int*)  d_in[0];
    const float* emb    = (const float*)d_in[2];
    const float* w_ih0  = (const float*)d_in[3];
    const float* w_hh0  = (const float*)d_in[4];
    const float* b_ih0  = (const float*)d_in[5];
    const float* b_hh0  = (const float*)d_in[6];
    const float* w_ih1  = (const float*)d_in[7];
    const float* w_hh1  = (const float*)d_in[8];
    const float* b_ih1  = (const float*)d_in[9];
    const float* b_hh1  = (const float*)d_in[10];
    const float* att_w  = (const float*)d_in[11];
    const float* att_b  = (const float*)d_in[12];
    const float* att_wv2= (const float*)d_in[13];
    const float* att_bv = (const float*)d_in[14];
    const float* att_wv1= (const float*)d_in[15];
    const float* fc_w   = (const float*)d_in[16];
    const float* fc_b   = (const float*)d_in[17];
    const float* cw[4] = {(const float*)d_in[18], (const float*)d_in[20],
                          (const float*)d_in[22], (const float*)d_in[24]};
    const float* cb[4] = {(const float*)d_in[19], (const float*)d_in[21],
                          (const float*)d_in[23], (const float*)d_in[25]};

    float* ws = (float*)d_ws;
    bf16*  GX   = (bf16*)ws;           // 32768*768 bf16 = 12,582,912 f32 slots
    float* H1   = ws + 12582912;       // 8,388,608 f ; later aliased as MATc
    float* H2   = H1 + 8388608;        // 8,388,608 f
    float* WT   = H2 + 8388608;        //   262,144 f (att_wT, then wv2T)
    float* WP   = WT + 262144;         //    65,536 f
    float* S    = WP + 65536;          //   131,072 f
    float* Aa   = S + 131072;
    float* AL   = Aa + 131072;
    float* AAa  = AL + 131072;
    float* NEW_ = AAa + 131072;
    float* NWD  = NEW_ + 131072;       //    32,768 f
    float* POOL = NWD + 32768;         //     1,792 f
    float* MATc = H1;                  // alias (H1 dead after layer-1 gemm)
    float* GV   = ws;                  // alias gx region (dead after scan 2)
    float* XWT  = ws;                  // alias (GV dead after gv_reduce)

    // layer 0 + scan
    gemm_mfma<bf16, true, 0><<<dim3(6, 256), 256, 0, stream>>>(
        emb, w_ih0, b_ih0, GX, utt, BLn, 768, En);
    gru_scan_reg<<<dim3(Bn, 2), 384, 0, stream>>>(GX, w_hh0, b_hh0, H1);
    // layer 1 + scan
    gemm_mfma<bf16, false, 0><<<dim3(6, 256), 256, 0, stream>>>(
        H1, w_ih1, b_ih1, GX, nullptr, BLn, 768, Dn);
    gru_scan_reg<<<dim3(Bn, 2), 384, 0, stream>>>(GX, w_hh1, b_hh1, H2);

    // scalar attention: mat_c = x @ att_w[c], fused tanh-sum scores
    transpose256<<<4, 256, 0, stream>>>(att_w, WT);
    for (int c = 0; c < 4; ++c) {
        gemm_mfma<float, false, 0><<<dim3(2, 256), 256, 0, stream>>>(
            H2, WT + (size_t)c * 65536, nullptr, MATc, nullptr, BLn, Dn, Dn);
        attn_score_mfma<<<dim3(2, Bn), 256, 0, stream>>>(
            H2, MATc, att_b, c, S + (size_t)c * 32768);
    }
    softmax256<<<Cn * Bn, 256, 0, stream>>>(S, Aa);

    // vector attention: gv = x @ wv2[c], reduce with sigmoid*wv1
    transpose256<<<4, 256, 0, stream>>>(att_wv2, WT);
    for (int c = 0; c < 4; ++c) {
        gemm_mfma<float, false, 0><<<dim3(2, 256), 256, 0, stream>>>(
            H2, WT + (size_t)c * 65536, nullptr, GV, nullptr, BLn, Dn, Dn);
        gv_reduce<<<BLn / 4, 256, 0, stream>>>(
            GV, att_bv + c * Dn, att_wv1 + c * Dn, AL + (size_t)c * BLn);
    }
    softmax256<<<Cn * Bn, 256, 0, stream>>>(AL, AAa);
    weighted_sum_kernel<<<dim3(Bn, Cn), 256, 0, stream>>>(AAa, H2, NEW_);

    // conv stage via xw GEMM decomposition (Cf never materialized)
    wpack_fill<<<5, 256, 0, stream>>>(cw[0], cw[1], cw[2], cw[3], WP);
    gemm_mfma<float, false, 1><<<dim3(2, 256), 256, 0, stream>>>(
        H2, WP, nullptr, XWT, nullptr, BLn, Dn, Dn);
    nwd_kernel<<<Bn, 256, 0, stream>>>(NEW_, WP, NWD);

    const int baserow[4] = {0, 16, 52, 116};
    const int poff[4]    = {0, 2, 5, 9};
    for (int f = 0; f < 4; ++f)
        conv_combine<<<Bn, 256, 0, stream>>>(XWT, Aa, NWD, cb[f], POOL, f + 2, baserow[f], poff[f]);

    fc_kernel<<<1, 256, 0, stream>>>(POOL, fc_w, fc_b, (float*)d_out);
}

// Round 10
// 1289.801 us; speedup vs baseline: 1.4747x; 1.0237x over previous
//
#include <hip/hip_runtime.h>
#include <hip/hip_bf16.h>
#include <hip/hip_fp16.h>

#define Bn  128
#define Ln  256
#define En  300
#define Hn  128
#define Cn  4
#define Dn  256     // 2H
#define G3n 384     // 3H
#define BLn (Bn * Ln)   // 32768

typedef __hip_bfloat16 bf16;
typedef short s16x8 __attribute__((ext_vector_type(8)));
typedef float f32x4 __attribute__((ext_vector_type(4)));
typedef _Float16 h16x2 __attribute__((ext_vector_type(2)));

__device__ __forceinline__ float ldf(const float* p) { return *p; }
__device__ __forceinline__ float ldf(const bf16* p)  { return __bfloat162float(*p); }
__device__ __forceinline__ void stf(float* p, float v) { *p = v; }
__device__ __forceinline__ void stf(bf16* p, float v)  { *p = __float2bfloat16(v); }

__device__ __forceinline__ ushort f2bf(float f) {
    bf16 h = __float2bfloat16(f);
    return *reinterpret_cast<ushort*>(&h);
}

#if __has_builtin(__builtin_amdgcn_fdot2)
__device__ __forceinline__ float dot2f(h16x2 w, h16x2 h, float c) {
    return __builtin_amdgcn_fdot2(w, h, c, false);
}
#else
__device__ __forceinline__ float dot2f(h16x2 w, h16x2 h, float c) {
    return fmaf((float)w[0], (float)h[0], fmaf((float)w[1], (float)h[1], c));
}
#endif
#define BCH(x) __builtin_bit_cast(h16x2, x)

// ---------------------------------------------------------------------------
// MFMA bf16 GEMM: C[M,N] = A[M,K] * W^T + bias   (W is (N,K) row-major)
//   GATHER: A row m = A[gidx[m]*K ..]    SM==1: store C[(m>>8),n,(m&255)]
// ---------------------------------------------------------------------------
template<class OT, bool GATHER, int SM>
__global__ __launch_bounds__(256)
void gemm_mfma(const float* __restrict__ A, const float* __restrict__ W,
               const float* __restrict__ bias, OT* __restrict__ Cout,
               const int* __restrict__ gidx, int M, int N, int K)
{
    __shared__ ushort Asm[128 * 40];
    __shared__ ushort Bsm[128 * 40];
    const int bm = blockIdx.y * 128, bn = blockIdx.x * 128;
    const int tid = threadIdx.x;
    const int lane = tid & 63, w = tid >> 6, wr = w >> 1, wc = w & 1;

    const float* arow[4];
    const float* brow[4];
#pragma unroll
    for (int u = 0; u < 4; ++u) {
        const int idx = tid + u * 256;
        const int m = idx >> 3;
        arow[u] = A + (size_t)(GATHER ? gidx[bm + m] : (bm + m)) * K;
        brow[u] = W + (size_t)(bn + m) * K;
    }

    f32x4 acc[4][4] = {};
    const int nkt = (K + 31) >> 5;
    for (int kt = 0; kt < nkt; ++kt) {
        const int k0 = kt << 5;
#pragma unroll
        for (int u = 0; u < 4; ++u) {
            const int idx = tid + u * 256;
            const int m = idx >> 3, kq = idx & 7;
            const int kb = k0 + kq * 4;
            float4 v, q;
            if (kb + 4 <= K) {
                v = *(const float4*)(arow[u] + kb);
                q = *(const float4*)(brow[u] + kb);
            } else {
                v.x = kb + 0 < K ? arow[u][kb + 0] : 0.f;
                v.y = kb + 1 < K ? arow[u][kb + 1] : 0.f;
                v.z = kb + 2 < K ? arow[u][kb + 2] : 0.f;
                v.w = kb + 3 < K ? arow[u][kb + 3] : 0.f;
                q.x = kb + 0 < K ? brow[u][kb + 0] : 0.f;
                q.y = kb + 1 < K ? brow[u][kb + 1] : 0.f;
                q.z = kb + 2 < K ? brow[u][kb + 2] : 0.f;
                q.w = kb + 3 < K ? brow[u][kb + 3] : 0.f;
            }
            *(ushort4*)&Asm[m * 40 + kq * 4] =
                make_ushort4(f2bf(v.x), f2bf(v.y), f2bf(v.z), f2bf(v.w));
            *(ushort4*)&Bsm[m * 40 + kq * 4] =
                make_ushort4(f2bf(q.x), f2bf(q.y), f2bf(q.z), f2bf(q.w));
        }
        __syncthreads();
        s16x8 af[4], bfr[4];
#pragma unroll
        for (int t = 0; t < 4; ++t) {
            af[t]  = *(const s16x8*)&Asm[(wr * 64 + t * 16 + (lane & 15)) * 40 + (lane >> 4) * 8];
            bfr[t] = *(const s16x8*)&Bsm[(wc * 64 + t * 16 + (lane & 15)) * 40 + (lane >> 4) * 8];
        }
#pragma unroll
        for (int mf = 0; mf < 4; ++mf)
#pragma unroll
            for (int nf = 0; nf < 4; ++nf)
                acc[mf][nf] = __builtin_amdgcn_mfma_f32_16x16x32_bf16(
                    af[mf], bfr[nf], acc[mf][nf], 0, 0, 0);
        __syncthreads();
    }

#pragma unroll
    for (int mf = 0; mf < 4; ++mf)
#pragma unroll
        for (int nf = 0; nf < 4; ++nf) {
            const int col = bn + wc * 64 + nf * 16 + (lane & 15);
            const float bv_ = bias ? bias[col] : 0.f;
#pragma unroll
            for (int i = 0; i < 4; ++i) {
                const int row = bm + wr * 64 + mf * 16 + (lane >> 4) * 4 + i;
                const float v = acc[mf][nf][i] + bv_;
                if (SM == 1)
                    stf(&Cout[((size_t)(row >> 8) * N + col) * 256 + (row & 255)], v);
                else
                    stf(&Cout[(size_t)row * N + col], v);
            }
        }
}

// ---------------------------------------------------------------------------
// GRU scan v7: LDS weights read as ds_read_b128 at 272B row stride.
// History: r3 L2-stream 900us; r5/r6/r9 VGPR attempts all demoted/spilled by
// the allocator (VGPR_Count 84/52/68 prove it) -> ~300-340us; r8 LDS-scalar
// was ISSUE-bound (64 ds_read_b32/thread/step ~2200cyc). This version is
// LDS-BANDWIDTH-bound by construction: weights as f16 pairs, row stride
// 272B (256+16 pad) -> b128 start bank (4r+4j)%32: lanes 0..7 cover all 32
// banks in disjoint 4-bank windows (conflict-free phases). h read via
// same-address b128 broadcasts (free). Floor: 98KB/step / 128B/cyc = 768
// cyc/step ~= 85us/scan; no compiler discretion involved.
// ---------------------------------------------------------------------------
__global__ __launch_bounds__(384, 1)
void gru_scan_b128(const bf16* __restrict__ gx, const float* __restrict__ w_hh,
                   const float* __restrict__ b_hh, float* __restrict__ out)
{
    const int b = blockIdx.x, dir = blockIdx.y;
    const int r = threadIdx.x;               // gate row 0..383
    __shared__ __align__(16) ushort wl[384 * 136];   // 272B rows, 104448 B
    __shared__ __align__(16) h16x2 hp[64];
    __shared__ float h_sh[128];
    __shared__ float rs[128], zs[128], gxn[128], ghn[128];

    // stage weights once (coalesced: 64 threads per row, banks 2-way = free)
    const float* wbase = w_hh + (size_t)dir * G3n * Hn;
    for (int idx = r; idx < G3n * 64; idx += 384) {
        const int row = idx >> 6, k2 = idx & 63;
        const float2 v = *(const float2*)(wbase + row * Hn + 2 * k2);
        h16x2 p; p[0] = (_Float16)v.x; p[1] = (_Float16)v.y;
        *(h16x2*)&wl[row * 136 + 2 * k2] = p;
    }
    if (r < 64) { h16x2 z; z[0] = (_Float16)0.f; z[1] = (_Float16)0.f; hp[r] = z; }
    if (r < 128) h_sh[r] = 0.f;
    const float bh = b_hh[dir * G3n + r];
    __syncthreads();

    const size_t g0 = (size_t)b * Ln * 768 + dir * G3n + r
                      + (dir ? (size_t)(Ln - 1) * 768 : 0);
    const long gstep = dir ? -768L : 768L;
    float gcur = ldf(&gx[g0]);
    float gnx  = ldf(&gx[g0 + gstep]);

    const ushort* wrow = &wl[r * 136];

    for (int s = 0; s < Ln; ++s) {
        const int t = dir ? (Ln - 1 - s) : s;
        float gn2 = 0.f;
        if (s + 2 < Ln) gn2 = ldf(&gx[g0 + (long)(s + 2) * gstep]);

        float a0 = 0.f, a1 = 0.f, a2 = 0.f, a3 = 0.f;
#pragma unroll
        for (int j = 0; j < 16; ++j) {
            const float4 wv = *(const float4*)&wrow[8 * j];      // 16B spread
            const float4 hv = *(const float4*)&hp[4 * j];        // 16B bcast
            a0 = dot2f(BCH(wv.x), BCH(hv.x), a0);
            a1 = dot2f(BCH(wv.y), BCH(hv.y), a1);
            a2 = dot2f(BCH(wv.z), BCH(hv.z), a2);
            a3 = dot2f(BCH(wv.w), BCH(hv.w), a3);
        }
        const float acc = (a0 + a1) + (a2 + a3) + bh;

        if (r < 128)      rs[r]       = 1.f / (1.f + expf(-(gcur + acc)));
        else if (r < 256) zs[r - 128] = 1.f / (1.f + expf(-(gcur + acc)));
        else { gxn[r - 256] = gcur; ghn[r - 256] = acc; }
        __syncthreads();

        if (r < 64) {
            const int j0 = 2 * r, j1 = j0 + 1;
            const float nn0 = tanhf(gxn[j0] + rs[j0] * ghn[j0]);
            const float nn1 = tanhf(gxn[j1] + rs[j1] * ghn[j1]);
            const float h0 = (1.f - zs[j0]) * nn0 + zs[j0] * h_sh[j0];
            const float h1 = (1.f - zs[j1]) * nn1 + zs[j1] * h_sh[j1];
            h_sh[j0] = h0; h_sh[j1] = h1;
            h16x2 pr; pr[0] = (_Float16)h0; pr[1] = (_Float16)h1;
            hp[r] = pr;
            *(float2*)&out[((size_t)b * Ln + t) * Dn + dir * Hn + j0] =
                make_float2(h0, h1);
        }
        __syncthreads();
        gcur = gnx; gnx = gn2;
    }
}

// ---------------------------------------------------------------------------
// attn score, MFMA: s[b,i] = sum_j tanh( x_b[i,:]·mat_b[j,:] + att_b[c] )
// ---------------------------------------------------------------------------
__global__ __launch_bounds__(256)
void attn_score_mfma(const float* __restrict__ x, const float* __restrict__ matc,
                     const float* __restrict__ attb, int c, float* __restrict__ sout)
{
    const int it = blockIdx.x, b = blockIdx.y;
    const float* A  = x    + ((size_t)b * 256 + it * 128) * 256;
    const float* Bm = matc + (size_t)b * 65536;
    __shared__ ushort Xs[128 * 40];
    __shared__ ushort Ms[128 * 40];
    const int tid = threadIdx.x, lane = tid & 63, w = tid >> 6;
    const float bc = attb[c];
    float psum[2][4] = {};

    for (int jt = 0; jt < 2; ++jt) {
        f32x4 acc[2][8] = {};
        for (int kt = 0; kt < 8; ++kt) {
            const int k0 = kt << 5;
#pragma unroll
            for (int u = 0; u < 4; ++u) {
                const int idx = tid + u * 256;
                const int m = idx >> 3, kq = idx & 7;
                const float4 v = *(const float4*)(A + (size_t)m * 256 + k0 + kq * 4);
                const float4 q = *(const float4*)(Bm + (size_t)(jt * 128 + m) * 256 + k0 + kq * 4);
                *(ushort4*)&Xs[m * 40 + kq * 4] =
                    make_ushort4(f2bf(v.x), f2bf(v.y), f2bf(v.z), f2bf(v.w));
                *(ushort4*)&Ms[m * 40 + kq * 4] =
                    make_ushort4(f2bf(q.x), f2bf(q.y), f2bf(q.z), f2bf(q.w));
            }
            __syncthreads();
            s16x8 af[2], bfr[8];
#pragma unroll
            for (int t = 0; t < 2; ++t)
                af[t] = *(const s16x8*)&Xs[(w * 32 + t * 16 + (lane & 15)) * 40 + (lane >> 4) * 8];
#pragma unroll
            for (int t = 0; t < 8; ++t)
                bfr[t] = *(const s16x8*)&Ms[(t * 16 + (lane & 15)) * 40 + (lane >> 4) * 8];
#pragma unroll
            for (int mf = 0; mf < 2; ++mf)
#pragma unroll
                for (int nf = 0; nf < 8; ++nf)
                    acc[mf][nf] = __builtin_amdgcn_mfma_f32_16x16x32_bf16(
                        af[mf], bfr[nf], acc[mf][nf], 0, 0, 0);
            __syncthreads();
        }
#pragma unroll
        for (int mf = 0; mf < 2; ++mf)
#pragma unroll
            for (int nf = 0; nf < 8; ++nf)
#pragma unroll
                for (int i = 0; i < 4; ++i)
                    psum[mf][i] += tanhf(acc[mf][nf][i] + bc);
    }

#pragma unroll
    for (int mf = 0; mf < 2; ++mf)
#pragma unroll
        for (int i = 0; i < 4; ++i) {
            float v = psum[mf][i];
            v += __shfl_xor(v, 1); v += __shfl_xor(v, 2);
            v += __shfl_xor(v, 4); v += __shfl_xor(v, 8);
            if ((lane & 15) == 0)
                sout[b * 256 + it * 128 + w * 32 + mf * 16 + (lane >> 4) * 4 + i] = v;
        }
}

// al[row] = sum_e sigmoid(gv[row,e] + bv[e]) * wv1[e]   (one wave per row)
__global__ __launch_bounds__(256)
void gv_reduce(const float* __restrict__ gv, const float* __restrict__ bv,
               const float* __restrict__ wv1, float* __restrict__ al)
{
    const int row = blockIdx.x * 4 + (threadIdx.x >> 6);
    const int l = threadIdx.x & 63;
    const float4 v  = *(const float4*)(gv + (size_t)row * 256 + l * 4);
    const float4 bb = *(const float4*)(bv + l * 4);
    const float4 w  = *(const float4*)(wv1 + l * 4);
    float s = w.x / (1.f + expf(-(v.x + bb.x)))
            + w.y / (1.f + expf(-(v.y + bb.y)))
            + w.z / (1.f + expf(-(v.z + bb.z)))
            + w.w / (1.f + expf(-(v.w + bb.w)));
#pragma unroll
    for (int m = 1; m < 64; m <<= 1) s += __shfl_xor(s, m);
    if (l == 0) al[row] = s;
}

// transpose 4 matrices of 256x256 (src[c][d][e] -> dst[c][e][d])
__global__ void transpose256(const float* __restrict__ src, float* __restrict__ dst)
{
    const float* s = src + (size_t)blockIdx.x * 65536;
    float* d = dst + (size_t)blockIdx.x * 65536;
    __shared__ float t[32][33];
    const int tx = threadIdx.x & 31, ty8 = threadIdx.x >> 5;
    for (int bi = 0; bi < 8; ++bi)
        for (int bj = 0; bj < 8; ++bj) {
            __syncthreads();
            for (int r = ty8; r < 32; r += 8)
                t[r][tx] = s[(size_t)(bi * 32 + r) * 256 + bj * 32 + tx];
            __syncthreads();
            for (int r = ty8; r < 32; r += 8)
                d[(size_t)(bj * 32 + r) * 256 + bi * 32 + tx] = t[tx][r];
        }
}

__global__ void softmax256(const float* __restrict__ in, float* __restrict__ out)
{
    __shared__ float red[256];
    const int row = blockIdx.x, t = threadIdx.x;
    const float v = in[(size_t)row * 256 + t];
    red[t] = v; __syncthreads();
    for (int off = 128; off; off >>= 1) {
        if (t < off) red[t] = fmaxf(red[t], red[t + off]);
        __syncthreads();
    }
    const float mx = red[0]; __syncthreads();
    const float e = expf(v - mx);
    red[t] = e; __syncthreads();
    for (int off = 128; off; off >>= 1) {
        if (t < off) red[t] += red[t + off];
        __syncthreads();
    }
    out[(size_t)row * 256 + t] = e / red[0];
}

// new[c,b,d] = sum_l aa[c,b,l] * x[b,l,d]
__global__ void weighted_sum_kernel(const float* __restrict__ aa,
                                    const float* __restrict__ x,
                                    float* __restrict__ outnew)
{
    const int b = blockIdx.x, c = blockIdx.y, d = threadIdx.x;
    __shared__ float w[Ln];
    w[d] = aa[((size_t)c * Bn + b) * Ln + d];
    __syncthreads();
    float acc = 0.f;
    for (int l = 0; l < Ln; ++l)
        acc += w[l] * x[((size_t)b * Ln + l) * Dn + d];
    outnew[((size_t)c * Bn + b) * Dn + d] = acc;
}

// pack conv filter rows (216) into 256x256 fp32 (rows 216+ zero)
__global__ void wpack_fill(const float* __restrict__ w0, const float* __restrict__ w1,
                           const float* __restrict__ w2, const float* __restrict__ w3,
                           float* __restrict__ wp)
{
    const int f = blockIdx.x;
    if (f < 4) {
        const int cnt[4]  = {4096, 9216, 16384, 25600};
        const int boff[4] = {0, 4096, 13312, 29696};
        const float* src = f == 0 ? w0 : f == 1 ? w1 : f == 2 ? w2 : w3;
        for (int i = threadIdx.x; i < cnt[f]; i += blockDim.x)
            wp[boff[f] + i] = src[i];
    } else {
        for (int i = threadIdx.x; i < 65536 - 55296; i += blockDim.x)
            wp[55296 + i] = 0.f;
    }
}

// nwd[b,row] = dot(new[c_of_row, b, :], wpack[row, :])
__global__ __launch_bounds__(256)
void nwd_kernel(const float* __restrict__ nw, const float* __restrict__ wp,
                float* __restrict__ nwd)
{
    const int b = blockIdx.x;
    __shared__ float ns[4][256];
    for (int i = threadIdx.x; i < 1024; i += 256)
        ns[i >> 8][i & 255] = nw[((size_t)((i >> 8) * Bn + b) << 8) + (i & 255)];
    __syncthreads();
    const int row = threadIdx.x;
    if (row < 216) {
        int f, base;
        if (row < 16)       { f = 0; base = 0; }
        else if (row < 52)  { f = 1; base = 16; }
        else if (row < 116) { f = 2; base = 52; }
        else                { f = 3; base = 116; }
        const int fs = f + 2, local = row - base;
        const int c = (local / fs) & 3;
        const float* wr = wp + (size_t)row * 256;
        float acc = 0.f;
        for (int k = 0; k < 256; ++k) acc += ns[c][k] * wr[k];
        nwd[b * 256 + row] = acc;
    }
}

// conv+relu+maxpool via decomposition over a-weighted x rows + new offset
__global__ __launch_bounds__(256)
void conv_combine(const float* __restrict__ xwT, const float* __restrict__ a,
                  const float* __restrict__ nwd, const float* __restrict__ cb,
                  float* __restrict__ pool, int fs, int base, int poff)
{
    const int b = blockIdx.x, tid = threadIdx.x;
    __shared__ float ash[4][256];
    __shared__ float basev[5];
    __shared__ float red[256];
    for (int i = tid; i < 1024; i += 256)
        ash[i >> 8][i & 255] = a[((size_t)((i >> 8) * Bn + b) << 8) + (i & 255)];
    if (tid < fs) {
        float s = cb[tid];
        for (int c = 0; c < 4; ++c)
            for (int kh = 0; kh < fs; ++kh)
                s += nwd[b * 256 + base + (tid * 4 + c) * fs + kh];
        basev[tid] = s;
    }
    __syncthreads();
    const int ni = Ln - fs + 1;
    const float* xb = xwT + ((size_t)b << 16);
    for (int o = 0; o < fs; ++o) {
        float best = 0.f;
        if (tid < ni) {
            float acc = basev[o];
            for (int c = 0; c < 4; ++c)
                for (int kh = 0; kh < fs; ++kh) {
                    const int row = base + (o * 4 + c) * fs + kh;
                    acc += ash[c][tid + kh] * xb[(row << 8) + tid + kh];
                }
            best = fmaxf(acc, 0.f);
        }
        red[tid] = best; __syncthreads();
        for (int off = 128; off; off >>= 1) {
            if (tid < off) red[tid] = fmaxf(red[tid], red[tid + off]);
            __syncthreads();
        }
        if (tid == 0) pool[b * 14 + poff + o] = red[0];
        __syncthreads();
    }
}

__global__ void fc_kernel(const float* __restrict__ pool, const float* __restrict__ fw,
                          const float* __restrict__ fb, float* __restrict__ out)
{
    const int i = threadIdx.x;           // 256 = B*OUT
    const int b = i >> 1, o = i & 1;
    float acc = fb[o];
#pragma unroll
    for (int f = 0; f < 14; ++f) acc += pool[b * 14 + f] * fw[o * 14 + f];
    out[i] = acc;
}

// ---------------------------------------------------------------------------
extern "C" void kernel_launch(void* const* d_in, const int* in_sizes, int n_in,
                              void* d_out, int out_size, void* d_ws, size_t ws_size,
                              hipStream_t stream)
{
    const int*   utt    = (const int*)  d_in[0];
    const float* emb    = (const float*)d_in[2];
    const float* w_ih0  = (const float*)d_in[3];
    const float* w_hh0  = (const float*)d_in[4];
    const float* b_ih0  = (const float*)d_in[5];
    const float* b_hh0  = (const float*)d_in[6];
    const float* w_ih1  = (const float*)d_in[7];
    const float* w_hh1  = (const float*)d_in[8];
    const float* b_ih1  = (const float*)d_in[9];
    const float* b_hh1  = (const float*)d_in[10];
    const float* att_w  = (const float*)d_in[11];
    const float* att_b  = (const float*)d_in[12];
    const float* att_wv2= (const float*)d_in[13];
    const float* att_bv = (const float*)d_in[14];
    const float* att_wv1= (const float*)d_in[15];
    const float* fc_w   = (const float*)d_in[16];
    const float* fc_b   = (const float*)d_in[17];
    const float* cw[4] = {(const float*)d_in[18], (const float*)d_in[20],
                          (const float*)d_in[22], (const float*)d_in[24]};
    const float* cb[4] = {(const float*)d_in[19], (const float*)d_in[21],
                          (const float*)d_in[23], (const float*)d_in[25]};

    float* ws = (float*)d_ws;
    bf16*  GX   = (bf16*)ws;           // 32768*768 bf16 = 12,582,912 f32 slots
    float* H1   = ws + 12582912;       // 8,388,608 f ; later aliased as MATc
    float* H2   = H1 + 8388608;        // 8,388,608 f
    float* WT   = H2 + 8388608;        //   262,144 f (att_wT, then wv2T)
    float* WP   = WT + 262144;         //    65,536 f
    float* S    = WP + 65536;          //   131,072 f
    float* Aa   = S + 131072;
    float* AL   = Aa + 131072;
    float* AAa  = AL + 131072;
    float* NEW_ = AAa + 131072;
    float* NWD  = NEW_ + 131072;       //    32,768 f
    float* POOL = NWD + 32768;         //     1,792 f
    float* MATc = H1;                  // alias (H1 dead after layer-1 gemm)
    float* GV   = ws;                  // alias gx region (dead after scan 2)
    float* XWT  = ws;                  // alias (GV dead after gv_reduce)

    // layer 0 + scan
    gemm_mfma<bf16, true, 0><<<dim3(6, 256), 256, 0, stream>>>(
        emb, w_ih0, b_ih0, GX, utt, BLn, 768, En);
    gru_scan_b128<<<dim3(Bn, 2), 384, 0, stream>>>(GX, w_hh0, b_hh0, H1);
    // layer 1 + scan
    gemm_mfma<bf16, false, 0><<<dim3(6, 256), 256, 0, stream>>>(
        H1, w_ih1, b_ih1, GX, nullptr, BLn, 768, Dn);
    gru_scan_b128<<<dim3(Bn, 2), 384, 0, stream>>>(GX, w_hh1, b_hh1, H2);

    // scalar attention: mat_c = x @ att_w[c], fused tanh-sum scores
    transpose256<<<4, 256, 0, stream>>>(att_w, WT);
    for (int c = 0; c < 4; ++c) {
        gemm_mfma<float, false, 0><<<dim3(2, 256), 256, 0, stream>>>(
            H2, WT + (size_t)c * 65536, nullptr, MATc, nullptr, BLn, Dn, Dn);
        attn_score_mfma<<<dim3(2, Bn), 256, 0, stream>>>(
            H2, MATc, att_b, c, S + (size_t)c * 32768);
    }
    softmax256<<<Cn * Bn, 256, 0, stream>>>(S, Aa);

    // vector attention: gv = x @ wv2[c], reduce with sigmoid*wv1
    transpose256<<<4, 256, 0, stream>>>(att_wv2, WT);
    for (int c = 0; c < 4; ++c) {
        gemm_mfma<float, false, 0><<<dim3(2, 256), 256, 0, stream>>>(
            H2, WT + (size_t)c * 65536, nullptr, GV, nullptr, BLn, Dn, Dn);
        gv_reduce<<<BLn / 4, 256, 0, stream>>>(
            GV, att_bv + c * Dn, att_wv1 + c * Dn, AL + (size_t)c * BLn);
    }
    softmax256<<<Cn * Bn, 256, 0, stream>>>(AL, AAa);
    weighted_sum_kernel<<<dim3(Bn, Cn), 256, 0, stream>>>(AAa, H2, NEW_);

    // conv stage via xw GEMM decomposition (Cf never materialized)
    wpack_fill<<<5, 256, 0, stream>>>(cw[0], cw[1], cw[2], cw[3], WP);
    gemm_mfma<float, false, 1><<<dim3(2, 256), 256, 0, stream>>>(
        H2, WP, nullptr, XWT, nullptr, BLn, Dn, Dn);
    nwd_kernel<<<Bn, 256, 0, stream>>>(NEW_, WP, NWD);

    const int baserow[4] = {0, 16, 52, 116};
    const int poff[4]    = {0, 2, 5, 9};
    for (int f = 0; f < 4; ++f)
        conv_combine<<<Bn, 256, 0, stream>>>(XWT, Aa, NWD, cb[f], POOL, f + 2, baserow[f], poff[f]);

    fc_kernel<<<1, 256, 0, stream>>>(POOL, fc_w, fc_b, (float*)d_out);
}